// Round 1
// baseline (852.404 us; speedup 1.0000x reference)
//
#include <hip/hip_runtime.h>
#include <hip/hip_bf16.h>

#define SGQ 4096
#define DMODEL 512
#define NH 8
#define DHEAD 64

typedef __attribute__((ext_vector_type(8))) short s16x8;
typedef __attribute__((ext_vector_type(4))) float f32x4;

__device__ inline ushort f2bf(float x) {
  unsigned u = __float_as_uint(x);
  return (ushort)((u + 0x7FFFu + ((u >> 16) & 1u)) >> 16);
}
__device__ inline float bf2f(ushort h) { return __uint_as_float(((unsigned)h) << 16); }

// ---------------- weight convert + transpose: W[K][N] f32 -> Wt[N][K] bf16 ----------------
__global__ __launch_bounds__(256) void wconv_kernel(const float* __restrict__ W,
                                                    ushort* __restrict__ Wt, int K, int N) {
  __shared__ float tile[32][33];
  int n0 = blockIdx.x * 32, k0 = blockIdx.y * 32;
  int tx = threadIdx.x & 31, ty = threadIdx.x >> 5;
  #pragma unroll
  for (int i = ty; i < 32; i += 8) tile[i][tx] = W[(size_t)(k0 + i) * N + n0 + tx];
  __syncthreads();
  #pragma unroll
  for (int i = ty; i < 32; i += 8) Wt[(size_t)(n0 + i) * K + k0 + tx] = f2bf(tile[tx][i]);
}

// ---------------- LayerNorm of embeds -> normed bf16; also embeds bf16 into cat[:,512:] ----
__global__ __launch_bounds__(256) void ln_prep_kernel(const float* __restrict__ x,
    const float* __restrict__ g, const float* __restrict__ b,
    ushort* __restrict__ normed, ushort* __restrict__ cat) {
  int row = blockIdx.x * 4 + (threadIdx.x >> 6);
  int lane = threadIdx.x & 63;
  const float* xr = x + (size_t)row * DMODEL + lane * 8;
  float4 p0 = *(const float4*)xr;
  float4 p1 = *(const float4*)(xr + 4);
  float v[8] = {p0.x, p0.y, p0.z, p0.w, p1.x, p1.y, p1.z, p1.w};
  float s = 0.f;
  #pragma unroll
  for (int j = 0; j < 8; ++j) s += v[j];
  #pragma unroll
  for (int m = 1; m <= 32; m <<= 1) s += __shfl_xor(s, m);
  float mu = s * (1.0f / DMODEL);
  float q = 0.f;
  #pragma unroll
  for (int j = 0; j < 8; ++j) { float d = v[j] - mu; q += d * d; }
  #pragma unroll
  for (int m = 1; m <= 32; m <<= 1) q += __shfl_xor(q, m);
  float rs = rsqrtf(q * (1.0f / DMODEL) + 1e-5f);
  s16x8 nout, eout;
  #pragma unroll
  for (int j = 0; j < 8; ++j) {
    int c = lane * 8 + j;
    nout[j] = (short)f2bf((v[j] - mu) * rs * g[c] + b[c]);
    eout[j] = (short)f2bf(v[j]);
  }
  *(s16x8*)(normed + (size_t)row * DMODEL + lane * 8) = nout;
  *(s16x8*)(cat + (size_t)row * 1024 + DMODEL + lane * 8) = eout;
}

// ---------------- LayerNorm + sigmoid -> gate bf16 ----------------
__global__ __launch_bounds__(256) void ln_sigmoid_kernel(const float* __restrict__ x,
    const float* __restrict__ g, const float* __restrict__ b, ushort* __restrict__ gate) {
  int row = blockIdx.x * 4 + (threadIdx.x >> 6);
  int lane = threadIdx.x & 63;
  const float* xr = x + (size_t)row * DMODEL + lane * 8;
  float4 p0 = *(const float4*)xr;
  float4 p1 = *(const float4*)(xr + 4);
  float v[8] = {p0.x, p0.y, p0.z, p0.w, p1.x, p1.y, p1.z, p1.w};
  float s = 0.f;
  #pragma unroll
  for (int j = 0; j < 8; ++j) s += v[j];
  #pragma unroll
  for (int m = 1; m <= 32; m <<= 1) s += __shfl_xor(s, m);
  float mu = s * (1.0f / DMODEL);
  float q = 0.f;
  #pragma unroll
  for (int j = 0; j < 8; ++j) { float d = v[j] - mu; q += d * d; }
  #pragma unroll
  for (int m = 1; m <= 32; m <<= 1) q += __shfl_xor(q, m);
  float rs = rsqrtf(q * (1.0f / DMODEL) + 1e-5f);
  s16x8 o;
  #pragma unroll
  for (int j = 0; j < 8; ++j) {
    int c = lane * 8 + j;
    float y = (v[j] - mu) * rs * g[c] + b[c];
    o[j] = (short)f2bf(1.0f / (1.0f + __expf(-y)));
  }
  *(s16x8*)(gate + (size_t)row * DMODEL + lane * 8) = o;
}

// ---------------- per-head l2norm split: q/k f32 [S][512] -> bf16 [H][S][64] ----------------
__global__ __launch_bounds__(256) void l2split_kernel(const float* __restrict__ x,
                                                      ushort* __restrict__ outHM, float scale) {
  int row = blockIdx.x * 4 + (threadIdx.x >> 6);
  int lane = threadIdx.x & 63;
  const float* xr = x + (size_t)row * DMODEL + lane * 8;
  float4 p0 = *(const float4*)xr;
  float4 p1 = *(const float4*)(xr + 4);
  float v[8] = {p0.x, p0.y, p0.z, p0.w, p1.x, p1.y, p1.z, p1.w};
  float ss = 0.f;
  #pragma unroll
  for (int j = 0; j < 8; ++j) ss += v[j] * v[j];
  ss += __shfl_xor(ss, 1); ss += __shfl_xor(ss, 2); ss += __shfl_xor(ss, 4);
  float n = sqrtf(ss);
  float sc = scale / fmaxf(n, 1e-12f);
  int h = lane >> 3;
  s16x8 o;
  #pragma unroll
  for (int j = 0; j < 8; ++j) o[j] = (short)f2bf(v[j] * sc);
  *(s16x8*)(outHM + ((size_t)h * SGQ + row) * DHEAD + (lane & 7) * 8) = o;
}

// ---------------- V transpose: vrow bf16 [S][512] -> vt [H][64][S] ----------------
__global__ __launch_bounds__(256) void vtrans_kernel(const ushort* __restrict__ vrow,
                                                     ushort* __restrict__ vt) {
  __shared__ ushort tile[64][68];
  int h = blockIdx.y;
  int s0 = blockIdx.x * 64;
  int c = threadIdx.x & 63;
  int rb = threadIdx.x >> 6;
  #pragma unroll
  for (int i = 0; i < 16; ++i) {
    int r = rb * 16 + i;
    tile[r][c] = vrow[(size_t)(s0 + r) * DMODEL + h * DHEAD + c];
  }
  __syncthreads();
  #pragma unroll
  for (int i = 0; i < 16; ++i) {
    int d = rb * 16 + i;
    vt[(size_t)(h * DHEAD + d) * SGQ + s0 + c] = tile[c][d];
  }
}

// ---------------- GEMM: C[S][512] = A[S][K](bf16,lda) @ Wt^T + bias ----------------
// EPI 0: fp32 out.  EPI 1: bf16 out.  EPI 2: out = emb + gate * (acc+bias)  (fp32 out)
template <int EPI>
__global__ __launch_bounds__(256) void gemm_kernel(
    const ushort* __restrict__ A, int lda, const ushort* __restrict__ Wt, int K,
    const float* __restrict__ bias, float* __restrict__ outF, ushort* __restrict__ outB,
    const float* __restrict__ emb, const ushort* __restrict__ gate) {
  int w = threadIdx.x >> 6, lane = threadIdx.x & 63;
  int ln = lane & 15, g = lane >> 4;
  int row0 = blockIdx.y * 64 + w * 16;
  int col0 = blockIdx.x * 64;
  const ushort* arow = A + (size_t)(row0 + ln) * lda + g * 8;
  f32x4 acc[4] = {{0.f,0.f,0.f,0.f},{0.f,0.f,0.f,0.f},{0.f,0.f,0.f,0.f},{0.f,0.f,0.f,0.f}};
  for (int k0 = 0; k0 < K; k0 += 32) {
    s16x8 a = *(const s16x8*)(arow + k0);
    #pragma unroll
    for (int j = 0; j < 4; ++j) {
      s16x8 bb = *(const s16x8*)(Wt + (size_t)(col0 + j * 16 + ln) * K + k0 + g * 8);
      acc[j] = __builtin_amdgcn_mfma_f32_16x16x32_bf16(a, bb, acc[j], 0, 0, 0);
    }
  }
  #pragma unroll
  for (int j = 0; j < 4; ++j) {
    int col = col0 + j * 16 + ln;
    float bv = bias[col];
    #pragma unroll
    for (int r = 0; r < 4; ++r) {
      int row = row0 + g * 4 + r;
      float vv = acc[j][r] + bv;
      if (EPI == 0) {
        outF[(size_t)row * DMODEL + col] = vv;
      } else if (EPI == 1) {
        outB[(size_t)row * DMODEL + col] = f2bf(vv);
      } else {
        float e = emb[(size_t)row * DMODEL + col];
        float gt = bf2f(gate[(size_t)row * DMODEL + col]);
        outF[(size_t)row * DMODEL + col] = e + gt * vv;
      }
    }
  }
}

// ---------------- attention: ctx = softmax(clip(qn@kn^T)) @ V, ctx -> cat[:,0:512] ----------
// qn: [H][Sq][64] bf16 (l2normed*0.125), kn: [H][Sk][64] bf16 (l2normed), vt: [H][64][Sk] bf16
__global__ __launch_bounds__(256) void attn_kernel(
    const ushort* __restrict__ qn, const ushort* __restrict__ kn,
    const ushort* __restrict__ vt, ushort* __restrict__ cat) {
  __shared__ __align__(16) ushort P[4][16][72];
  const int w = threadIdx.x >> 6, lane = threadIdx.x & 63;
  const int ln = lane & 15, g = lane >> 4;
  const int h = blockIdx.y;
  const int r0 = blockIdx.x * 64 + w * 16;
  const ushort* qbase = qn + ((size_t)h * SGQ + r0) * DHEAD;
  s16x8 aq0 = *(const s16x8*)(qbase + ln * DHEAD + g * 8);
  s16x8 aq1 = *(const s16x8*)(qbase + ln * DHEAD + 32 + g * 8);
  const ushort* knh = kn + (size_t)h * SGQ * DHEAD;
  const ushort* vth = vt + (size_t)h * DHEAD * SGQ;
  f32x4 o[4] = {{0.f,0.f,0.f,0.f},{0.f,0.f,0.f,0.f},{0.f,0.f,0.f,0.f},{0.f,0.f,0.f,0.f}};
  float rowsum[4] = {0.f, 0.f, 0.f, 0.f};
  for (int key0 = 0; key0 < SGQ; key0 += 64) {
    f32x4 s4[4] = {{0.f,0.f,0.f,0.f},{0.f,0.f,0.f,0.f},{0.f,0.f,0.f,0.f},{0.f,0.f,0.f,0.f}};
    #pragma unroll
    for (int j = 0; j < 4; ++j) {
      const ushort* kb = knh + (size_t)(key0 + j * 16 + ln) * DHEAD + g * 8;
      s16x8 b0 = *(const s16x8*)(kb);
      s16x8 b1 = *(const s16x8*)(kb + 32);
      s4[j] = __builtin_amdgcn_mfma_f32_16x16x32_bf16(aq0, b0, s4[j], 0, 0, 0);
      s4[j] = __builtin_amdgcn_mfma_f32_16x16x32_bf16(aq1, b1, s4[j], 0, 0, 0);
    }
    #pragma unroll
    for (int j = 0; j < 4; ++j) {
      #pragma unroll
      for (int r = 0; r < 4; ++r) {
        float p = s4[j][r];
        p = fminf(fmaxf(p, -10.f), 10.f);
        p = __expf(p);
        rowsum[r] += p;
        P[w][g * 4 + r][j * 16 + ln] = f2bf(p);
      }
    }
    __syncthreads();
    s16x8 ap0 = *(const s16x8*)(&P[w][ln][g * 8]);
    s16x8 ap1 = *(const s16x8*)(&P[w][ln][32 + g * 8]);
    #pragma unroll
    for (int j = 0; j < 4; ++j) {
      const ushort* vb = vth + (size_t)(j * 16 + ln) * SGQ + key0 + g * 8;
      s16x8 b0 = *(const s16x8*)(vb);
      s16x8 b1 = *(const s16x8*)(vb + 32);
      o[j] = __builtin_amdgcn_mfma_f32_16x16x32_bf16(ap0, b0, o[j], 0, 0, 0);
      o[j] = __builtin_amdgcn_mfma_f32_16x16x32_bf16(ap1, b1, o[j], 0, 0, 0);
    }
  }
  #pragma unroll
  for (int r = 0; r < 4; ++r) {
    float v = rowsum[r];
    v += __shfl_xor(v, 1); v += __shfl_xor(v, 2); v += __shfl_xor(v, 4); v += __shfl_xor(v, 8);
    rowsum[r] = v;
  }
  #pragma unroll
  for (int j = 0; j < 4; ++j) {
    #pragma unroll
    for (int r = 0; r < 4; ++r) {
      int row = r0 + g * 4 + r;
      int col = h * DHEAD + j * 16 + ln;
      cat[(size_t)row * 1024 + col] = f2bf(o[j][r] / rowsum[r]);
    }
  }
}

extern "C" void kernel_launch(void* const* d_in, const int* in_sizes, int n_in,
                              void* d_out, int out_size, void* d_ws, size_t ws_size,
                              hipStream_t stream) {
  const float* gene = (const float*)d_in[0];
  const float* drug = (const float*)d_in[1];
  const float* lng_g = (const float*)d_in[2];
  const float* lng_b = (const float*)d_in[3];
  const float* lnd_g = (const float*)d_in[4];
  const float* lnd_b = (const float*)d_in[5];
  const float* wgq = (const float*)d_in[6];  const float* bgq = (const float*)d_in[7];
  const float* wgk = (const float*)d_in[8];  const float* bgk = (const float*)d_in[9];
  const float* wgv = (const float*)d_in[10]; const float* bgv = (const float*)d_in[11];
  const float* wdq = (const float*)d_in[12]; const float* bdq = (const float*)d_in[13];
  const float* wdk = (const float*)d_in[14]; const float* bdk = (const float*)d_in[15];
  const float* wdv = (const float*)d_in[16]; const float* bdv = (const float*)d_in[17];
  const float* wo  = (const float*)d_in[18]; const float* bo  = (const float*)d_in[19];
  const float* wgg = (const float*)d_in[20]; const float* bgg = (const float*)d_in[21];
  const float* gg_g = (const float*)d_in[22]; const float* gg_b = (const float*)d_in[23];
  const float* wdg = (const float*)d_in[24]; const float* bdg = (const float*)d_in[25];
  const float* dg_g = (const float*)d_in[26]; const float* dg_b = (const float*)d_in[27];
  float* out = (float*)d_out;

  char* p = (char*)d_ws;
  size_t off = 0;
  auto alloc = [&](size_t bytes) { char* r = p + off; off = (off + bytes + 255) & ~(size_t)255; return r; };
  ushort* wT_gq = (ushort*)alloc(512 * 512 * 2);
  ushort* wT_gk = (ushort*)alloc(512 * 512 * 2);
  ushort* wT_gv = (ushort*)alloc(512 * 512 * 2);
  ushort* wT_dq = (ushort*)alloc(512 * 512 * 2);
  ushort* wT_dk = (ushort*)alloc(512 * 512 * 2);
  ushort* wT_dv = (ushort*)alloc(512 * 512 * 2);
  ushort* wT_o  = (ushort*)alloc(512 * 512 * 2);
  ushort* wT_gg = (ushort*)alloc(1024 * 512 * 2);
  ushort* wT_dg = (ushort*)alloc(1024 * 512 * 2);
  ushort* ng   = (ushort*)alloc((size_t)SGQ * 512 * 2);
  ushort* nd   = (ushort*)alloc((size_t)SGQ * 512 * 2);
  ushort* catg = (ushort*)alloc((size_t)SGQ * 1024 * 2);
  ushort* catd = (ushort*)alloc((size_t)SGQ * 1024 * 2);
  ushort* qn_g = (ushort*)alloc((size_t)SGQ * 512 * 2);
  ushort* kn_g = (ushort*)alloc((size_t)SGQ * 512 * 2);
  ushort* qn_d = (ushort*)alloc((size_t)SGQ * 512 * 2);
  ushort* kn_d = (ushort*)alloc((size_t)SGQ * 512 * 2);
  ushort* vt_g = (ushort*)alloc((size_t)SGQ * 512 * 2);
  ushort* vt_d = (ushort*)alloc((size_t)SGQ * 512 * 2);
  ushort* gate_g = (ushort*)alloc((size_t)SGQ * 512 * 2);
  ushort* gate_d = (ushort*)alloc((size_t)SGQ * 512 * 2);
  float*  tmpF = (float*)alloc((size_t)SGQ * 512 * 4);
  ushort* tmpB = (ushort*)tmpF;  // reuse as bf16 scratch for v-rows

  dim3 blk(256);
  // weights -> bf16 transposed
  wconv_kernel<<<dim3(16, 16), blk, 0, stream>>>(wgq, wT_gq, 512, 512);
  wconv_kernel<<<dim3(16, 16), blk, 0, stream>>>(wgk, wT_gk, 512, 512);
  wconv_kernel<<<dim3(16, 16), blk, 0, stream>>>(wgv, wT_gv, 512, 512);
  wconv_kernel<<<dim3(16, 16), blk, 0, stream>>>(wdq, wT_dq, 512, 512);
  wconv_kernel<<<dim3(16, 16), blk, 0, stream>>>(wdk, wT_dk, 512, 512);
  wconv_kernel<<<dim3(16, 16), blk, 0, stream>>>(wdv, wT_dv, 512, 512);
  wconv_kernel<<<dim3(16, 16), blk, 0, stream>>>(wo,  wT_o,  512, 512);
  wconv_kernel<<<dim3(16, 32), blk, 0, stream>>>(wgg, wT_gg, 1024, 512);
  wconv_kernel<<<dim3(16, 32), blk, 0, stream>>>(wdg, wT_dg, 1024, 512);

  // LayerNorm + embed bf16 into cat
  ln_prep_kernel<<<dim3(1024), blk, 0, stream>>>(gene, lng_g, lng_b, ng, catg);
  ln_prep_kernel<<<dim3(1024), blk, 0, stream>>>(drug, lnd_g, lnd_b, nd, catd);

  dim3 ggrid(8, 64);
  // gene q/k/v
  gemm_kernel<0><<<ggrid, blk, 0, stream>>>(ng, 512, wT_gq, 512, bgq, tmpF, nullptr, nullptr, nullptr);
  l2split_kernel<<<dim3(1024), blk, 0, stream>>>(tmpF, qn_g, 0.125f);
  gemm_kernel<0><<<ggrid, blk, 0, stream>>>(ng, 512, wT_gk, 512, bgk, tmpF, nullptr, nullptr, nullptr);
  l2split_kernel<<<dim3(1024), blk, 0, stream>>>(tmpF, kn_g, 1.0f);
  gemm_kernel<1><<<ggrid, blk, 0, stream>>>(catg + 512, 1024, wT_gv, 512, bgv, nullptr, tmpB, nullptr, nullptr);
  vtrans_kernel<<<dim3(64, 8), blk, 0, stream>>>(tmpB, vt_g);
  // drug q/k/v
  gemm_kernel<0><<<ggrid, blk, 0, stream>>>(nd, 512, wT_dq, 512, bdq, tmpF, nullptr, nullptr, nullptr);
  l2split_kernel<<<dim3(1024), blk, 0, stream>>>(tmpF, qn_d, 0.125f);
  gemm_kernel<0><<<ggrid, blk, 0, stream>>>(nd, 512, wT_dk, 512, bdk, tmpF, nullptr, nullptr, nullptr);
  l2split_kernel<<<dim3(1024), blk, 0, stream>>>(tmpF, kn_d, 1.0f);
  gemm_kernel<1><<<ggrid, blk, 0, stream>>>(catd + 512, 1024, wT_dv, 512, bdv, nullptr, tmpB, nullptr, nullptr);
  vtrans_kernel<<<dim3(64, 8), blk, 0, stream>>>(tmpB, vt_d);

  // cross attention: gene queries x drug K/V ; drug queries x gene K/V
  attn_kernel<<<dim3(64, 8), blk, 0, stream>>>(qn_g, kn_d, vt_d, catg);
  attn_kernel<<<dim3(64, 8), blk, 0, stream>>>(qn_d, kn_g, vt_g, catd);

  // gates
  gemm_kernel<0><<<ggrid, blk, 0, stream>>>(catg, 1024, wT_gg, 1024, bgg, tmpF, nullptr, nullptr, nullptr);
  ln_sigmoid_kernel<<<dim3(1024), blk, 0, stream>>>(tmpF, gg_g, gg_b, gate_g);
  gemm_kernel<0><<<ggrid, blk, 0, stream>>>(catd, 1024, wT_dg, 1024, bdg, tmpF, nullptr, nullptr, nullptr);
  ln_sigmoid_kernel<<<dim3(1024), blk, 0, stream>>>(tmpF, dg_g, dg_b, gate_d);

  // final: out = emb + gate * (ctx @ wo + bo)
  gemm_kernel<2><<<ggrid, blk, 0, stream>>>(catg, 1024, wT_o, 512, bo, out, nullptr, gene, gate_g);
  gemm_kernel<2><<<ggrid, blk, 0, stream>>>(catd, 1024, wT_o, 512, bo, out + (size_t)SGQ * 512, nullptr, drug, gate_d);
}

// Round 3
// 348.020 us; speedup vs baseline: 2.4493x; 2.4493x over previous
//
#include <hip/hip_runtime.h>
#include <hip/hip_bf16.h>

#define SGQ 4096
#define DMODEL 512
#define NH 8
#define DHEAD 64

typedef __attribute__((ext_vector_type(8))) short s16x8;
typedef __attribute__((ext_vector_type(4))) float f32x4;

__device__ inline ushort f2bf(float x) {
  unsigned u = __float_as_uint(x);
  return (ushort)((u + 0x7FFFu + ((u >> 16) & 1u)) >> 16);
}
__device__ inline float bf2f(ushort h) { return __uint_as_float(((unsigned)h) << 16); }

// ================= merged weight convert+transpose: W[K][N] f32 -> Wt[N][K] bf16 ===========
struct WArgs { const float* w[9]; ushort* wt[9]; int K[9]; };

__global__ __launch_bounds__(256) void wconv_kernel(WArgs args) {
  __shared__ float tile[32][33];
  int z = blockIdx.z;
  int K = args.K[z];
  int k0 = blockIdx.y * 32;
  if (k0 >= K) return;
  const float* W = args.w[z];
  ushort* Wt = args.wt[z];
  int n0 = blockIdx.x * 32;
  int tx = threadIdx.x & 31, ty = threadIdx.x >> 5;
  #pragma unroll
  for (int i = ty; i < 32; i += 8) tile[i][tx] = W[(size_t)(k0 + i) * DMODEL + n0 + tx];
  __syncthreads();
  #pragma unroll
  for (int i = ty; i < 32; i += 8) Wt[(size_t)(n0 + i) * K + k0 + tx] = f2bf(tile[tx][i]);
}

// ================= LayerNorm -> normed bf16; embeds bf16 -> cat[:,512:] (both sides) ======
struct LArgs { const float* x[2]; const float* gg[2]; const float* bb[2]; ushort* normed[2]; ushort* cat[2]; };

__global__ __launch_bounds__(256) void ln_prep_kernel(LArgs args) {
  int side = blockIdx.y;
  int row = blockIdx.x * 4 + (threadIdx.x >> 6);
  int lane = threadIdx.x & 63;
  const float* xr = args.x[side] + (size_t)row * DMODEL + lane * 8;
  float4 p0 = *(const float4*)xr;
  float4 p1 = *(const float4*)(xr + 4);
  float v[8] = {p0.x, p0.y, p0.z, p0.w, p1.x, p1.y, p1.z, p1.w};
  float s = 0.f;
  #pragma unroll
  for (int j = 0; j < 8; ++j) s += v[j];
  #pragma unroll
  for (int m = 1; m <= 32; m <<= 1) s += __shfl_xor(s, m);
  float mu = s * (1.0f / DMODEL);
  float q = 0.f;
  #pragma unroll
  for (int j = 0; j < 8; ++j) { float d = v[j] - mu; q += d * d; }
  #pragma unroll
  for (int m = 1; m <= 32; m <<= 1) q += __shfl_xor(q, m);
  float rs = rsqrtf(q * (1.0f / DMODEL) + 1e-5f);
  const float* g = args.gg[side];
  const float* b = args.bb[side];
  s16x8 nout, eout;
  #pragma unroll
  for (int j = 0; j < 8; ++j) {
    int c = lane * 8 + j;
    nout[j] = (short)f2bf((v[j] - mu) * rs * g[c] + b[c]);
    eout[j] = (short)f2bf(v[j]);
  }
  *(s16x8*)(args.normed[side] + (size_t)row * DMODEL + lane * 8) = nout;
  *(s16x8*)(args.cat[side] + (size_t)row * 1024 + DMODEL + lane * 8) = eout;
}

// ================= LayerNorm + sigmoid -> gate bf16 (both sides) ==========================
struct SArgs { const float* x[2]; const float* gg[2]; const float* bb[2]; ushort* gate[2]; };

__global__ __launch_bounds__(256) void ln_sigmoid_kernel(SArgs args) {
  int side = blockIdx.y;
  int row = blockIdx.x * 4 + (threadIdx.x >> 6);
  int lane = threadIdx.x & 63;
  const float* xr = args.x[side] + (size_t)row * DMODEL + lane * 8;
  float4 p0 = *(const float4*)xr;
  float4 p1 = *(const float4*)(xr + 4);
  float v[8] = {p0.x, p0.y, p0.z, p0.w, p1.x, p1.y, p1.z, p1.w};
  float s = 0.f;
  #pragma unroll
  for (int j = 0; j < 8; ++j) s += v[j];
  #pragma unroll
  for (int m = 1; m <= 32; m <<= 1) s += __shfl_xor(s, m);
  float mu = s * (1.0f / DMODEL);
  float q = 0.f;
  #pragma unroll
  for (int j = 0; j < 8; ++j) { float d = v[j] - mu; q += d * d; }
  #pragma unroll
  for (int m = 1; m <= 32; m <<= 1) q += __shfl_xor(q, m);
  float rs = rsqrtf(q * (1.0f / DMODEL) + 1e-5f);
  const float* g = args.gg[side];
  const float* b = args.bb[side];
  s16x8 o;
  #pragma unroll
  for (int j = 0; j < 8; ++j) {
    int c = lane * 8 + j;
    float y = (v[j] - mu) * rs * g[c] + b[c];
    o[j] = (short)f2bf(1.0f / (1.0f + __expf(-y)));
  }
  *(s16x8*)(args.gate[side] + (size_t)row * DMODEL + lane * 8) = o;
}

// ================= shared GEMM core: one wave computes 16 rows x 64 cols ==================
// K is both the contraction extent and Wt's leading dimension; lda is A's leading dim.
__device__ inline void gemm_core(const ushort* __restrict__ A, int lda,
                                 const ushort* __restrict__ Wt, int K,
                                 int rowA, int col0, int ln, int g, f32x4 acc[4]) {
  const ushort* arow = A + (size_t)rowA * lda + g * 8;
  const ushort* brow = Wt + (size_t)(col0 + ln) * K + g * 8;
  for (int k0 = 0; k0 < K; k0 += 32) {
    s16x8 a = *(const s16x8*)(arow + k0);
    #pragma unroll
    for (int j = 0; j < 4; ++j) {
      s16x8 bb = *(const s16x8*)(brow + (size_t)j * 16 * K + k0);
      acc[j] = __builtin_amdgcn_mfma_f32_16x16x32_bf16(a, bb, acc[j], 0, 0, 0);
    }
  }
}

// ================= merged q/k/v projections, fused l2norm-split / V-transpose ============
// z: 0=gq 1=gk 2=gv 3=dq 4=dk 5=dv.  q/k: dst = [H][S][64] bf16 l2normed*scale.
// v: dst = [H][64][S] bf16 (transposed).
struct QArgs {
  const ushort* A[6]; const ushort* Wt[6]; const float* bias[6];
  ushort* dst[6]; int lda[6]; float scale[6]; int isV[6];
};

__global__ __launch_bounds__(256) void qkv_kernel(QArgs args) {
  __shared__ ushort t[64][72];
  const int z = blockIdx.z;
  const int w = threadIdx.x >> 6, lane = threadIdx.x & 63;
  const int ln = lane & 15, g = lane >> 4;
  const int h = blockIdx.x;             // col block == head
  const int row0 = blockIdx.y * 64 + w * 16;
  const int col0 = h * 64;
  f32x4 zero = {0.f, 0.f, 0.f, 0.f};
  f32x4 acc[4] = {zero, zero, zero, zero};
  gemm_core(args.A[z], args.lda[z], args.Wt[z], DMODEL, row0 + ln, col0, ln, g, acc);
  const float* bias = args.bias[z];
  ushort* dst = args.dst[z];
  if (!args.isV[z]) {
    // add bias, per-row l2 norm over this head's 64 cols, scale, write [H][S][64]
    float ss[4] = {0.f, 0.f, 0.f, 0.f};
    #pragma unroll
    for (int j = 0; j < 4; ++j) {
      float bv = bias[col0 + j * 16 + ln];
      #pragma unroll
      for (int r = 0; r < 4; ++r) {
        float v = acc[j][r] + bv;
        acc[j][r] = v;
        ss[r] += v * v;
      }
    }
    #pragma unroll
    for (int r = 0; r < 4; ++r) {
      float v = ss[r];
      v += __shfl_xor(v, 1); v += __shfl_xor(v, 2);
      v += __shfl_xor(v, 4); v += __shfl_xor(v, 8);
      ss[r] = args.scale[z] / fmaxf(sqrtf(v), 1e-12f);
    }
    #pragma unroll
    for (int j = 0; j < 4; ++j)
      #pragma unroll
      for (int r = 0; r < 4; ++r) {
        int row = row0 + g * 4 + r;
        dst[((size_t)h * SGQ + row) * 64 + j * 16 + ln] = f2bf(acc[j][r] * ss[r]);
      }
  } else {
    // transpose via LDS -> [H][64][S]
    #pragma unroll
    for (int j = 0; j < 4; ++j) {
      float bv = bias[col0 + j * 16 + ln];
      #pragma unroll
      for (int r = 0; r < 4; ++r)
        t[j * 16 + ln][w * 16 + g * 4 + r] = f2bf(acc[j][r] + bv);
    }
    __syncthreads();
    int dh = threadIdx.x >> 2;
    int kc = (threadIdx.x & 3) * 16;
    s16x8 v0 = *(const s16x8*)&t[dh][kc];
    s16x8 v1 = *(const s16x8*)&t[dh][kc + 8];
    size_t base = (size_t)(h * 64 + dh) * SGQ + blockIdx.y * 64 + kc;
    *(s16x8*)&dst[base] = v0;
    *(s16x8*)&dst[base + 8] = v1;
  }
}

// ================= attention, both sides, LDS-staged double-buffered K/V =================
// qn[s]: [H][Sq][64] (l2*0.125), kn[s]: opposite side's K [H][Sk][64], vt[s]: [H][64][Sk]
struct AArgs { const ushort* qn[2]; const ushort* kn[2]; const ushort* vt[2]; ushort* cat[2]; };

__global__ __launch_bounds__(256, 2) void attn_kernel(AArgs args) {
  __shared__ __align__(16) ushort Ksh[2][64 * 64];
  __shared__ __align__(16) ushort Vsh[2][64 * 64];
  __shared__ __align__(16) ushort Psh[4][32 * 64];

  const int side = blockIdx.z, h = blockIdx.y, qb = blockIdx.x;
  const int w = threadIdx.x >> 6, lane = threadIdx.x & 63;
  const int ln = lane & 15, g = lane >> 4;
  const int l8 = lane & 7, lr = lane >> 3;

  const ushort* qn = args.qn[side];
  const ushort* knh = args.kn[side] + (size_t)h * SGQ * 64;
  const ushort* vth = args.vt[side] + (size_t)h * 64 * SGQ;
  ushort* cat = args.cat[side];

  const int r0 = qb * 128 + w * 32;
  s16x8 aq[2][2];
  #pragma unroll
  for (int rb = 0; rb < 2; ++rb)
    #pragma unroll
    for (int kh = 0; kh < 2; ++kh)
      aq[rb][kh] = *(const s16x8*)(qn + ((size_t)h * SGQ + r0 + rb * 16 + ln) * 64 + kh * 32 + g * 8);

  const int krow0 = w * 16;  // this wave stages rows [krow0, krow0+16)
  s16x8 sk[2], sv[2];

  // prologue: load tile 0 into regs
  #pragma unroll
  for (int c = 0; c < 2; ++c) {
    int row = krow0 + c * 8 + lr;
    sk[c] = *(const s16x8*)(knh + (size_t)row * 64 + l8 * 8);
    sv[c] = *(const s16x8*)(vth + (size_t)row * SGQ + l8 * 8);
  }

  f32x4 zero = {0.f, 0.f, 0.f, 0.f};
  f32x4 o[2][4];
  float rsum[2][4];
  #pragma unroll
  for (int rb = 0; rb < 2; ++rb)
    #pragma unroll
    for (int j = 0; j < 4; ++j) { o[rb][j] = zero; rsum[rb][j] = 0.f; }

  for (int t = 0; t < SGQ / 64; ++t) {
    const int cur = t & 1;
    // write staged regs into LDS (compiler waits vmcnt for reg deps)
    #pragma unroll
    for (int c = 0; c < 2; ++c) {
      int row = krow0 + c * 8 + lr;
      int colsw = (l8 * 8) ^ ((row & 7) << 3);
      *(s16x8*)&Ksh[cur][row * 64 + colsw] = sk[c];
      *(s16x8*)&Vsh[cur][row * 64 + colsw] = sv[c];
    }
    asm volatile("s_waitcnt lgkmcnt(0)" ::: "memory");
    __builtin_amdgcn_s_barrier();
    asm volatile("" ::: "memory");
    // issue next-tile loads; they overlap the compute below
    if (t < SGQ / 64 - 1) {
      int key0 = (t + 1) << 6;
      #pragma unroll
      for (int c = 0; c < 2; ++c) {
        int row = krow0 + c * 8 + lr;
        sk[c] = *(const s16x8*)(knh + (size_t)(key0 + row) * 64 + l8 * 8);
        sv[c] = *(const s16x8*)(vth + (size_t)row * SGQ + key0 + l8 * 8);
      }
    }
    // ---- QK^T: 16 MFMAs ----
    f32x4 s[2][4];
    #pragma unroll
    for (int rb = 0; rb < 2; ++rb)
      #pragma unroll
      for (int j = 0; j < 4; ++j) s[rb][j] = zero;
    #pragma unroll
    for (int j = 0; j < 4; ++j) {
      int kr = j * 16 + ln;
      int sw = (kr & 7) << 3;
      s16x8 kb0 = *(const s16x8*)&Ksh[cur][kr * 64 + ((g * 8) ^ sw)];
      s16x8 kb1 = *(const s16x8*)&Ksh[cur][kr * 64 + ((32 + g * 8) ^ sw)];
      s[0][j] = __builtin_amdgcn_mfma_f32_16x16x32_bf16(aq[0][0], kb0, s[0][j], 0, 0, 0);
      s[0][j] = __builtin_amdgcn_mfma_f32_16x16x32_bf16(aq[0][1], kb1, s[0][j], 0, 0, 0);
      s[1][j] = __builtin_amdgcn_mfma_f32_16x16x32_bf16(aq[1][0], kb0, s[1][j], 0, 0, 0);
      s[1][j] = __builtin_amdgcn_mfma_f32_16x16x32_bf16(aq[1][1], kb1, s[1][j], 0, 0, 0);
    }
    // ---- exp + rowsum + P (clip(-10,10) is a provable no-op: |score| <= 0.125) ----
    #pragma unroll
    for (int rb = 0; rb < 2; ++rb)
      #pragma unroll
      for (int j = 0; j < 4; ++j) {
        int pcol = j * 16 + ln;
        #pragma unroll
        for (int r = 0; r < 4; ++r) {
          float p = __expf(s[rb][j][r]);
          rsum[rb][r] += p;
          int prow = rb * 16 + g * 4 + r;
          Psh[w][prow * 64 + (pcol ^ ((prow & 7) << 3))] = f2bf(p);
        }
      }
    // ---- P·V: 16 MFMAs ----
    s16x8 pa[2][2];
    #pragma unroll
    for (int rb = 0; rb < 2; ++rb) {
      int prow = rb * 16 + ln;
      int sw = (prow & 7) << 3;
      pa[rb][0] = *(const s16x8*)&Psh[w][prow * 64 + ((g * 8) ^ sw)];
      pa[rb][1] = *(const s16x8*)&Psh[w][prow * 64 + ((32 + g * 8) ^ sw)];
    }
    #pragma unroll
    for (int j = 0; j < 4; ++j) {
      int vr = j * 16 + ln;
      int sw = (vr & 7) << 3;
      s16x8 vb0 = *(const s16x8*)&Vsh[cur][vr * 64 + ((g * 8) ^ sw)];
      s16x8 vb1 = *(const s16x8*)&Vsh[cur][vr * 64 + ((32 + g * 8) ^ sw)];
      o[0][j] = __builtin_amdgcn_mfma_f32_16x16x32_bf16(pa[0][0], vb0, o[0][j], 0, 0, 0);
      o[0][j] = __builtin_amdgcn_mfma_f32_16x16x32_bf16(pa[0][1], vb1, o[0][j], 0, 0, 0);
      o[1][j] = __builtin_amdgcn_mfma_f32_16x16x32_bf16(pa[1][0], vb0, o[1][j], 0, 0, 0);
      o[1][j] = __builtin_amdgcn_mfma_f32_16x16x32_bf16(pa[1][1], vb1, o[1][j], 0, 0, 0);
    }
  }
  // ---- epilogue: reduce rowsums across ln lanes, divide, write ctx -> cat[:,0:512] ----
  float inv[2][4];
  #pragma unroll
  for (int rb = 0; rb < 2; ++rb)
    #pragma unroll
    for (int r = 0; r < 4; ++r) {
      float v = rsum[rb][r];
      v += __shfl_xor(v, 1); v += __shfl_xor(v, 2);
      v += __shfl_xor(v, 4); v += __shfl_xor(v, 8);
      inv[rb][r] = 1.0f / v;
    }
  #pragma unroll
  for (int rb = 0; rb < 2; ++rb)
    #pragma unroll
    for (int j = 0; j < 4; ++j)
      #pragma unroll
      for (int r = 0; r < 4; ++r) {
        int row = r0 + rb * 16 + g * 4 + r;
        cat[(size_t)row * 1024 + h * 64 + j * 16 + ln] = f2bf(o[rb][j][r] * inv[rb][r]);
      }
}

// ================= gate pre-LN GEMM (K=1024) both sides -> f32 ============================
struct GArgs { const ushort* A[2]; const ushort* Wt[2]; const float* bias[2]; float* outF[2]; };

__global__ __launch_bounds__(256) void gate_gemm_kernel(GArgs args) {
  const int z = blockIdx.z;
  const int w = threadIdx.x >> 6, lane = threadIdx.x & 63;
  const int ln = lane & 15, g = lane >> 4;
  const int row0 = blockIdx.y * 64 + w * 16;
  const int col0 = blockIdx.x * 64;
  f32x4 zero = {0.f, 0.f, 0.f, 0.f};
  f32x4 acc[4] = {zero, zero, zero, zero};
  gemm_core(args.A[z], 1024, args.Wt[z], 1024, row0 + ln, col0, ln, g, acc);
  float* outF = args.outF[z];
  #pragma unroll
  for (int j = 0; j < 4; ++j) {
    int col = col0 + j * 16 + ln;
    float bv = args.bias[z][col];
    #pragma unroll
    for (int r = 0; r < 4; ++r)
      outF[(size_t)(row0 + g * 4 + r) * DMODEL + col] = acc[j][r] + bv;
  }
}

// ================= final output GEMM: out = emb + gate * (ctx@wo + bo), both sides ========
// NOTE: contraction is over ctx only -> K=512 (wo's leading dim), A lda=1024.
struct OArgs {
  const ushort* A[2]; const ushort* Wt; const float* bias;
  const float* emb[2]; const ushort* gate[2]; float* out[2];
};

__global__ __launch_bounds__(256) void out_gemm_kernel(OArgs args) {
  const int z = blockIdx.z;
  const int w = threadIdx.x >> 6, lane = threadIdx.x & 63;
  const int ln = lane & 15, g = lane >> 4;
  const int row0 = blockIdx.y * 64 + w * 16;
  const int col0 = blockIdx.x * 64;
  f32x4 zero = {0.f, 0.f, 0.f, 0.f};
  f32x4 acc[4] = {zero, zero, zero, zero};
  gemm_core(args.A[z], 1024, args.Wt, 512, row0 + ln, col0, ln, g, acc);
  const float* emb = args.emb[z];
  const ushort* gate = args.gate[z];
  float* out = args.out[z];
  #pragma unroll
  for (int j = 0; j < 4; ++j) {
    int col = col0 + j * 16 + ln;
    float bv = args.bias[col];
    #pragma unroll
    for (int r = 0; r < 4; ++r) {
      size_t idx = (size_t)(row0 + g * 4 + r) * DMODEL + col;
      out[idx] = emb[idx] + bf2f(gate[idx]) * (acc[j][r] + bv);
    }
  }
}

// ================= host ====================================================================
extern "C" void kernel_launch(void* const* d_in, const int* in_sizes, int n_in,
                              void* d_out, int out_size, void* d_ws, size_t ws_size,
                              hipStream_t stream) {
  const float* gene = (const float*)d_in[0];
  const float* drug = (const float*)d_in[1];
  const float* lng_g = (const float*)d_in[2];
  const float* lng_b = (const float*)d_in[3];
  const float* lnd_g = (const float*)d_in[4];
  const float* lnd_b = (const float*)d_in[5];
  const float* wgq = (const float*)d_in[6];  const float* bgq = (const float*)d_in[7];
  const float* wgk = (const float*)d_in[8];  const float* bgk = (const float*)d_in[9];
  const float* wgv = (const float*)d_in[10]; const float* bgv = (const float*)d_in[11];
  const float* wdq = (const float*)d_in[12]; const float* bdq = (const float*)d_in[13];
  const float* wdk = (const float*)d_in[14]; const float* bdk = (const float*)d_in[15];
  const float* wdv = (const float*)d_in[16]; const float* bdv = (const float*)d_in[17];
  const float* wo  = (const float*)d_in[18]; const float* bo  = (const float*)d_in[19];
  const float* wgg = (const float*)d_in[20]; const float* bgg = (const float*)d_in[21];
  const float* gg_g = (const float*)d_in[22]; const float* gg_b = (const float*)d_in[23];
  const float* wdg = (const float*)d_in[24]; const float* bdg = (const float*)d_in[25];
  const float* dg_g = (const float*)d_in[26]; const float* dg_b = (const float*)d_in[27];
  float* out = (float*)d_out;

  char* p = (char*)d_ws;
  size_t off = 0;
  auto alloc = [&](size_t bytes) { char* r = p + off; off = (off + bytes + 255) & ~(size_t)255; return r; };
  ushort* wT_gq = (ushort*)alloc(512 * 512 * 2);
  ushort* wT_gk = (ushort*)alloc(512 * 512 * 2);
  ushort* wT_gv = (ushort*)alloc(512 * 512 * 2);
  ushort* wT_dq = (ushort*)alloc(512 * 512 * 2);
  ushort* wT_dk = (ushort*)alloc(512 * 512 * 2);
  ushort* wT_dv = (ushort*)alloc(512 * 512 * 2);
  ushort* wT_o  = (ushort*)alloc(512 * 512 * 2);
  ushort* wT_gg = (ushort*)alloc(1024 * 512 * 2);
  ushort* wT_dg = (ushort*)alloc(1024 * 512 * 2);
  ushort* ng   = (ushort*)alloc((size_t)SGQ * 512 * 2);
  ushort* nd   = (ushort*)alloc((size_t)SGQ * 512 * 2);
  ushort* catg = (ushort*)alloc((size_t)SGQ * 1024 * 2);
  ushort* catd = (ushort*)alloc((size_t)SGQ * 1024 * 2);
  ushort* qn_g = (ushort*)alloc((size_t)SGQ * 512 * 2);
  ushort* kn_g = (ushort*)alloc((size_t)SGQ * 512 * 2);
  ushort* qn_d = (ushort*)alloc((size_t)SGQ * 512 * 2);
  ushort* kn_d = (ushort*)alloc((size_t)SGQ * 512 * 2);
  ushort* vt_g = (ushort*)alloc((size_t)SGQ * 512 * 2);
  ushort* vt_d = (ushort*)alloc((size_t)SGQ * 512 * 2);
  // dead-buffer reuse after attention:
  float*  tmpF_g = (float*)qn_g;   // 8 MB spans qn_g+kn_g (contiguous, 256-aligned)
  float*  tmpF_d = (float*)qn_d;   // 8 MB spans qn_d+kn_d
  ushort* gate_g = vt_g;
  ushort* gate_d = vt_d;

  dim3 blk(256);

  WArgs wa;
  {
    const float* ws_[9] = {wgq, wgk, wgv, wdq, wdk, wdv, wo, wgg, wdg};
    ushort* wt_[9] = {wT_gq, wT_gk, wT_gv, wT_dq, wT_dk, wT_dv, wT_o, wT_gg, wT_dg};
    int k_[9] = {512, 512, 512, 512, 512, 512, 512, 1024, 1024};
    for (int i = 0; i < 9; ++i) { wa.w[i] = ws_[i]; wa.wt[i] = wt_[i]; wa.K[i] = k_[i]; }
  }
  wconv_kernel<<<dim3(16, 32, 9), blk, 0, stream>>>(wa);

  LArgs la;
  la.x[0] = gene; la.x[1] = drug;
  la.gg[0] = lng_g; la.gg[1] = lnd_g;
  la.bb[0] = lng_b; la.bb[1] = lnd_b;
  la.normed[0] = ng; la.normed[1] = nd;
  la.cat[0] = catg; la.cat[1] = catd;
  ln_prep_kernel<<<dim3(1024, 2), blk, 0, stream>>>(la);

  QArgs qa;
  {
    const ushort* A_[6] = {ng, ng, catg + 512, nd, nd, catd + 512};
    const ushort* W_[6] = {wT_gq, wT_gk, wT_gv, wT_dq, wT_dk, wT_dv};
    const float* B_[6] = {bgq, bgk, bgv, bdq, bdk, bdv};
    ushort* D_[6] = {qn_g, kn_g, vt_g, qn_d, kn_d, vt_d};
    int lda_[6] = {512, 512, 1024, 512, 512, 1024};
    float sc_[6] = {0.125f, 1.0f, 0.f, 0.125f, 1.0f, 0.f};
    int iv_[6] = {0, 0, 1, 0, 0, 1};
    for (int i = 0; i < 6; ++i) {
      qa.A[i] = A_[i]; qa.Wt[i] = W_[i]; qa.bias[i] = B_[i];
      qa.dst[i] = D_[i]; qa.lda[i] = lda_[i]; qa.scale[i] = sc_[i]; qa.isV[i] = iv_[i];
    }
  }
  qkv_kernel<<<dim3(8, 64, 6), blk, 0, stream>>>(qa);

  AArgs aa;
  aa.qn[0] = qn_g; aa.qn[1] = qn_d;
  aa.kn[0] = kn_d; aa.kn[1] = kn_g;   // cross: gene-q attends drug-K/V, and vice versa
  aa.vt[0] = vt_d; aa.vt[1] = vt_g;
  aa.cat[0] = catg; aa.cat[1] = catd;
  attn_kernel<<<dim3(32, 8, 2), blk, 0, stream>>>(aa);

  GArgs ga;
  ga.A[0] = catg; ga.A[1] = catd;
  ga.Wt[0] = wT_gg; ga.Wt[1] = wT_dg;
  ga.bias[0] = bgg; ga.bias[1] = bdg;
  ga.outF[0] = tmpF_g; ga.outF[1] = tmpF_d;
  gate_gemm_kernel<<<dim3(8, 64, 2), blk, 0, stream>>>(ga);

  SArgs sa;
  sa.x[0] = tmpF_g; sa.x[1] = tmpF_d;
  sa.gg[0] = gg_g; sa.gg[1] = dg_g;
  sa.bb[0] = gg_b; sa.bb[1] = dg_b;
  sa.gate[0] = gate_g; sa.gate[1] = gate_d;
  ln_sigmoid_kernel<<<dim3(1024, 2), blk, 0, stream>>>(sa);

  OArgs oa;
  oa.A[0] = catg; oa.A[1] = catd;
  oa.Wt = wT_o; oa.bias = bo;
  oa.emb[0] = gene; oa.emb[1] = drug;
  oa.gate[0] = gate_g; oa.gate[1] = gate_d;
  oa.out[0] = out; oa.out[1] = out + (size_t)SGQ * 512;
  out_gemm_kernel<<<dim3(8, 64, 2), blk, 0, stream>>>(oa);
}

// Round 4
// 183.027 us; speedup vs baseline: 4.6572x; 1.9015x over previous
//
#include <hip/hip_runtime.h>
#include <hip/hip_bf16.h>

#define SGQ 4096
#define DMODEL 512
#define NH 8
#define DHEAD 64

typedef __attribute__((ext_vector_type(8))) short s16x8;
typedef __attribute__((ext_vector_type(4))) float f32x4;
typedef __attribute__((ext_vector_type(16))) float f32x16;
typedef __attribute__((ext_vector_type(4))) unsigned int u32x4;

__device__ inline ushort f2bf(float x) {
  unsigned u = __float_as_uint(x);
  return (ushort)((u + 0x7FFFu + ((u >> 16) & 1u)) >> 16);
}
__device__ inline float bf2f(ushort h) { return __uint_as_float(((unsigned)h) << 16); }

// ================= merged weight convert+transpose: W[K][N] f32 -> Wt[N][K] bf16 ===========
struct WArgs { const float* w[9]; ushort* wt[9]; int K[9]; };

__global__ __launch_bounds__(256) void wconv_kernel(WArgs args) {
  __shared__ float tile[32][33];
  int z = blockIdx.z;
  int K = args.K[z];
  int k0 = blockIdx.y * 32;
  if (k0 >= K) return;
  const float* W = args.w[z];
  ushort* Wt = args.wt[z];
  int n0 = blockIdx.x * 32;
  int tx = threadIdx.x & 31, ty = threadIdx.x >> 5;
  #pragma unroll
  for (int i = ty; i < 32; i += 8) tile[i][tx] = W[(size_t)(k0 + i) * DMODEL + n0 + tx];
  __syncthreads();
  #pragma unroll
  for (int i = ty; i < 32; i += 8) Wt[(size_t)(n0 + i) * K + k0 + tx] = f2bf(tile[tx][i]);
}

// ================= LayerNorm -> normed bf16; embeds bf16 -> cat[:,512:] (both sides) ======
struct LArgs { const float* x[2]; const float* gg[2]; const float* bb[2]; ushort* normed[2]; ushort* cat[2]; };

__global__ __launch_bounds__(256) void ln_prep_kernel(LArgs args) {
  int side = blockIdx.y;
  int row = blockIdx.x * 4 + (threadIdx.x >> 6);
  int lane = threadIdx.x & 63;
  const float* xr = args.x[side] + (size_t)row * DMODEL + lane * 8;
  float4 p0 = *(const float4*)xr;
  float4 p1 = *(const float4*)(xr + 4);
  float v[8] = {p0.x, p0.y, p0.z, p0.w, p1.x, p1.y, p1.z, p1.w};
  float s = 0.f;
  #pragma unroll
  for (int j = 0; j < 8; ++j) s += v[j];
  #pragma unroll
  for (int m = 1; m <= 32; m <<= 1) s += __shfl_xor(s, m);
  float mu = s * (1.0f / DMODEL);
  float q = 0.f;
  #pragma unroll
  for (int j = 0; j < 8; ++j) { float d = v[j] - mu; q += d * d; }
  #pragma unroll
  for (int m = 1; m <= 32; m <<= 1) q += __shfl_xor(q, m);
  float rs = rsqrtf(q * (1.0f / DMODEL) + 1e-5f);
  const float* g = args.gg[side];
  const float* b = args.bb[side];
  s16x8 nout, eout;
  #pragma unroll
  for (int j = 0; j < 8; ++j) {
    int c = lane * 8 + j;
    nout[j] = (short)f2bf((v[j] - mu) * rs * g[c] + b[c]);
    eout[j] = (short)f2bf(v[j]);
  }
  *(s16x8*)(args.normed[side] + (size_t)row * DMODEL + lane * 8) = nout;
  *(s16x8*)(args.cat[side] + (size_t)row * 1024 + DMODEL + lane * 8) = eout;
}

// ================= LayerNorm + sigmoid -> gate bf16 (both sides) ==========================
struct SArgs { const float* x[2]; const float* gg[2]; const float* bb[2]; ushort* gate[2]; };

__global__ __launch_bounds__(256) void ln_sigmoid_kernel(SArgs args) {
  int side = blockIdx.y;
  int row = blockIdx.x * 4 + (threadIdx.x >> 6);
  int lane = threadIdx.x & 63;
  const float* xr = args.x[side] + (size_t)row * DMODEL + lane * 8;
  float4 p0 = *(const float4*)xr;
  float4 p1 = *(const float4*)(xr + 4);
  float v[8] = {p0.x, p0.y, p0.z, p0.w, p1.x, p1.y, p1.z, p1.w};
  float s = 0.f;
  #pragma unroll
  for (int j = 0; j < 8; ++j) s += v[j];
  #pragma unroll
  for (int m = 1; m <= 32; m <<= 1) s += __shfl_xor(s, m);
  float mu = s * (1.0f / DMODEL);
  float q = 0.f;
  #pragma unroll
  for (int j = 0; j < 8; ++j) { float d = v[j] - mu; q += d * d; }
  #pragma unroll
  for (int m = 1; m <= 32; m <<= 1) q += __shfl_xor(q, m);
  float rs = rsqrtf(q * (1.0f / DMODEL) + 1e-5f);
  const float* g = args.gg[side];
  const float* b = args.bb[side];
  s16x8 o;
  #pragma unroll
  for (int j = 0; j < 8; ++j) {
    int c = lane * 8 + j;
    float y = (v[j] - mu) * rs * g[c] + b[c];
    o[j] = (short)f2bf(1.0f / (1.0f + __expf(-y)));
  }
  *(s16x8*)(args.gate[side] + (size_t)row * DMODEL + lane * 8) = o;
}

// ================= unified 128x128-tile LDS-staged GEMM ===================================
// C = A[M x K](bf16, lda) @ Wt[N][K]^T.  4 waves, each owns a 64x64 quadrant.
// EPI 0: qkv (isV? transposed-V write : per-head l2norm+scale write)
// EPI 1: f32 out (gate pre-LN)
// EPI 2: out = emb + gate * (acc + bias)
struct GemmDesc {
  const ushort* A; const ushort* Wt; const float* bias;
  void* dst; const float* emb; const ushort* gate;
  int lda; int K; float scale; int isV;
};
struct GemmArgs { GemmDesc d[6]; };

template <int EPI>
__global__ __launch_bounds__(256) void gemm_tiled(GemmArgs args) {
  __shared__ __align__(16) ushort Ash[2][128 * 32];
  __shared__ __align__(16) ushort Bsh[2][128 * 32];
  const GemmDesc& D = args.d[blockIdx.z];
  const int tid = threadIdx.x;
  const int w = tid >> 6, lane = tid & 63;
  const int ln = lane & 15, g = lane >> 4;
  const int wr = w >> 1, wc = w & 1;
  const int rowT = blockIdx.y * 128, colT = blockIdx.x * 128;
  const int K = D.K, lda = D.lda;
  const ushort* Ag = D.A + (size_t)rowT * lda;
  const ushort* Bg = D.Wt + (size_t)colT * K;
  const int srow = tid >> 2;   // staging: c*64+srow = tile row, sq = k-granule
  const int sq = tid & 3;

  s16x8 ra[2], rb[2];
  #pragma unroll
  for (int c = 0; c < 2; ++c) {
    int row = c * 64 + srow;
    ra[c] = *(const s16x8*)(Ag + (size_t)row * lda + sq * 8);
    rb[c] = *(const s16x8*)(Bg + (size_t)row * K + sq * 8);
  }

  f32x4 zero = {0.f, 0.f, 0.f, 0.f};
  f32x4 acc[4][4];
  #pragma unroll
  for (int m = 0; m < 4; ++m)
    #pragma unroll
    for (int n = 0; n < 4; ++n) acc[m][n] = zero;

  const int nT = K >> 5;
  for (int t = 0; t < nT; ++t) {
    const int cur = t & 1;
    #pragma unroll
    for (int c = 0; c < 2; ++c) {
      int row = c * 64 + srow;
      int off = row * 32 + ((sq * 8) ^ (((row >> 1) & 3) << 3));
      *(s16x8*)&Ash[cur][off] = ra[c];
      *(s16x8*)&Bsh[cur][off] = rb[c];
    }
    asm volatile("s_waitcnt lgkmcnt(0)" ::: "memory");
    __builtin_amdgcn_s_barrier();
    asm volatile("" ::: "memory");
    if (t + 1 < nT) {
      int k0 = (t + 1) * 32;
      #pragma unroll
      for (int c = 0; c < 2; ++c) {
        int row = c * 64 + srow;
        ra[c] = *(const s16x8*)(Ag + (size_t)row * lda + k0 + sq * 8);
        rb[c] = *(const s16x8*)(Bg + (size_t)row * K + k0 + sq * 8);
      }
    }
    s16x8 af[4], bf[4];
    #pragma unroll
    for (int m = 0; m < 4; ++m) {
      int arow = wr * 64 + m * 16 + ln;
      af[m] = *(const s16x8*)&Ash[cur][arow * 32 + ((g * 8) ^ (((arow >> 1) & 3) << 3))];
      int brow = wc * 64 + m * 16 + ln;
      bf[m] = *(const s16x8*)&Bsh[cur][brow * 32 + ((g * 8) ^ (((brow >> 1) & 3) << 3))];
    }
    #pragma unroll
    for (int m = 0; m < 4; ++m)
      #pragma unroll
      for (int n = 0; n < 4; ++n)
        acc[m][n] = __builtin_amdgcn_mfma_f32_16x16x32_bf16(af[m], bf[n], acc[m][n], 0, 0, 0);
  }

  const float* bias = D.bias;
  const int colw = colT + wc * 64;
  if (EPI == 0) {
    const int h = colw >> 6;
    if (!D.isV) {
      float sc[4][4];
      #pragma unroll
      for (int m = 0; m < 4; ++m) {
        float ss[4] = {0.f, 0.f, 0.f, 0.f};
        #pragma unroll
        for (int n = 0; n < 4; ++n) {
          float bv = bias[colw + n * 16 + ln];
          #pragma unroll
          for (int r = 0; r < 4; ++r) {
            float v = acc[m][n][r] + bv;
            acc[m][n][r] = v;
            ss[r] += v * v;
          }
        }
        #pragma unroll
        for (int r = 0; r < 4; ++r) {
          float v = ss[r];
          v += __shfl_xor(v, 1); v += __shfl_xor(v, 2);
          v += __shfl_xor(v, 4); v += __shfl_xor(v, 8);
          sc[m][r] = D.scale / fmaxf(sqrtf(v), 1e-12f);
        }
      }
      ushort* dst = (ushort*)D.dst;
      #pragma unroll
      for (int m = 0; m < 4; ++m)
        #pragma unroll
        for (int n = 0; n < 4; ++n)
          #pragma unroll
          for (int r = 0; r < 4; ++r) {
            int row = rowT + wr * 64 + m * 16 + g * 4 + r;
            dst[((size_t)h * SGQ + row) * DHEAD + n * 16 + ln] = f2bf(acc[m][n][r] * sc[m][r]);
          }
    } else {
      ushort* dst = (ushort*)D.dst;
      #pragma unroll
      for (int m = 0; m < 4; ++m)
        #pragma unroll
        for (int n = 0; n < 4; ++n) {
          int d = n * 16 + ln;
          float bv = bias[colw + d];
          uint lo = (uint)f2bf(acc[m][n][0] + bv) | ((uint)f2bf(acc[m][n][1] + bv) << 16);
          uint hi2 = (uint)f2bf(acc[m][n][2] + bv) | ((uint)f2bf(acc[m][n][3] + bv) << 16);
          int s0 = rowT + wr * 64 + m * 16 + g * 4;
          uint2 pk; pk.x = lo; pk.y = hi2;
          *(uint2*)(dst + (size_t)(h * DHEAD + d) * SGQ + s0) = pk;
        }
    }
  } else if (EPI == 1) {
    float* outF = (float*)D.dst;
    #pragma unroll
    for (int m = 0; m < 4; ++m)
      #pragma unroll
      for (int n = 0; n < 4; ++n) {
        float bv = bias[colw + n * 16 + ln];
        #pragma unroll
        for (int r = 0; r < 4; ++r)
          outF[(size_t)(rowT + wr * 64 + m * 16 + g * 4 + r) * DMODEL + colw + n * 16 + ln] =
              acc[m][n][r] + bv;
      }
  } else {
    float* outO = (float*)D.dst;
    #pragma unroll
    for (int m = 0; m < 4; ++m)
      #pragma unroll
      for (int n = 0; n < 4; ++n) {
        float bv = bias[colw + n * 16 + ln];
        #pragma unroll
        for (int r = 0; r < 4; ++r) {
          size_t idx = (size_t)(rowT + wr * 64 + m * 16 + g * 4 + r) * DMODEL + colw + n * 16 + ln;
          outO[idx] = D.emb[idx] + bf2f(D.gate[idx]) * (acc[m][n][r] + bv);
        }
      }
  }
}

// ================= attention: 32x32 swapped-operand MFMA, P in registers =================
// qn[s]: [H][Sq][64] (l2*0.125), kn[s]: opposite K [H][Sk][64], vt[s]: [H][64][Sk]
// QK^T computed as S^T = mfma(A=K_perm, B=Q); K A-rows loaded with bit2<->bit3-swapped
// index so each lane's C regs hold consecutive k: regs 0-7 -> k hi*8+0..7,
// regs 8-15 -> k 16+hi*8+0..7.  cvt_pk pairs then feed PV's A-fragment directly.
struct AArgs { const ushort* qn[2]; const ushort* kn[2]; const ushort* vt[2]; ushort* cat[2]; };

__global__ __launch_bounds__(256, 2) void attn_kernel(AArgs args) {
  __shared__ __align__(16) ushort Ksh[2][64 * 64];
  __shared__ __align__(16) ushort Vsh[2][64 * 64];
  const int side = blockIdx.z, h = blockIdx.y, qb = blockIdx.x;
  const int w = threadIdx.x >> 6, lane = threadIdx.x & 63;
  const int l32 = lane & 31, hi = lane >> 5;
  const int l8 = lane & 7, lr = lane >> 3;
  const ushort* qnh = args.qn[side] + (size_t)h * SGQ * DHEAD;
  const ushort* knh = args.kn[side] + (size_t)h * SGQ * DHEAD;
  const ushort* vth = args.vt[side] + (size_t)h * DHEAD * SGQ;
  ushort* cat = args.cat[side];
  const int r0w = qb * 128 + w * 32;

  s16x8 qf[4];
  #pragma unroll
  for (int s = 0; s < 4; ++s)
    qf[s] = *(const s16x8*)(qnh + (size_t)(r0w + l32) * DHEAD + s * 16 + hi * 8);

  const int krow0 = w * 16;  // this wave stages K/V rows [krow0, krow0+16)
  s16x8 sk[2], sv[2];
  #pragma unroll
  for (int c = 0; c < 2; ++c) {
    int row = krow0 + c * 8 + lr;
    sk[c] = *(const s16x8*)(knh + (size_t)row * DHEAD + l8 * 8);
    sv[c] = *(const s16x8*)(vth + (size_t)row * SGQ + l8 * 8);
  }

  const f32x16 Z = {0,0,0,0,0,0,0,0,0,0,0,0,0,0,0,0};
  f32x16 o0 = Z, o1 = Z;
  float rs0 = 0.f, rs1 = 0.f;
  const int krp = (l32 & 19) | ((l32 & 4) << 1) | ((l32 & 8) >> 1);  // swap bits 2<->3

  for (int t = 0; t < SGQ / 64; ++t) {
    const int cur = t & 1;
    #pragma unroll
    for (int c = 0; c < 2; ++c) {
      int row = krow0 + c * 8 + lr;
      int colsw = (l8 * 8) ^ ((row & 7) << 3);
      *(s16x8*)&Ksh[cur][row * 64 + colsw] = sk[c];
      *(s16x8*)&Vsh[cur][row * 64 + colsw] = sv[c];
    }
    asm volatile("s_waitcnt lgkmcnt(0)" ::: "memory");
    __builtin_amdgcn_s_barrier();
    asm volatile("" ::: "memory");
    if (t < SGQ / 64 - 1) {
      const int key0 = (t + 1) << 6;
      #pragma unroll
      for (int c = 0; c < 2; ++c) {
        int row = krow0 + c * 8 + lr;
        sk[c] = *(const s16x8*)(knh + (size_t)(key0 + row) * DHEAD + l8 * 8);
        sv[c] = *(const s16x8*)(vth + (size_t)row * SGQ + key0 + l8 * 8);
      }
    }
    #pragma unroll
    for (int st = 0; st < 2; ++st) {
      const int kr = st * 32 + krp;
      const int rsw = (kr & 7) << 3;
      f32x16 S = Z;
      __builtin_amdgcn_s_setprio(1);
      #pragma unroll
      for (int s = 0; s < 4; ++s) {
        s16x8 ka = *(const s16x8*)&Ksh[cur][kr * 64 + ((s * 16 + hi * 8) ^ rsw)];
        S = __builtin_amdgcn_mfma_f32_32x32x16_bf16(ka, qf[s], S, 0, 0, 0);
      }
      __builtin_amdgcn_s_setprio(0);
      // clip(-10,10) is a provable no-op: |score| <= 0.125
      float p[16];
      #pragma unroll
      for (int i = 0; i < 16; ++i) p[i] = __expf(S[i]);
      #pragma unroll
      for (int i = 0; i < 16; i += 2) { rs0 += p[i]; rs1 += p[i + 1]; }
      uint u[8];
      #pragma unroll
      for (int j = 0; j < 8; ++j) {
        uint r_;
        asm("v_cvt_pk_bf16_f32 %0, %1, %2" : "=v"(r_) : "v"(p[2 * j]), "v"(p[2 * j + 1]));
        u[j] = r_;
      }
      __builtin_amdgcn_s_setprio(1);
      #pragma unroll
      for (int slot = 0; slot < 2; ++slot) {
        u32x4 uv = {u[slot * 4 + 0], u[slot * 4 + 1], u[slot * 4 + 2], u[slot * 4 + 3]};
        s16x8 pf = __builtin_bit_cast(s16x8, uv);
        const int kc = st * 32 + slot * 16 + hi * 8;
        {
          int vr = l32;
          s16x8 vb = *(const s16x8*)&Vsh[cur][vr * 64 + (kc ^ ((vr & 7) << 3))];
          o0 = __builtin_amdgcn_mfma_f32_32x32x16_bf16(pf, vb, o0, 0, 0, 0);
        }
        {
          int vr = 32 + l32;
          s16x8 vb = *(const s16x8*)&Vsh[cur][vr * 64 + (kc ^ ((vr & 7) << 3))];
          o1 = __builtin_amdgcn_mfma_f32_32x32x16_bf16(pf, vb, o1, 0, 0, 0);
        }
      }
      __builtin_amdgcn_s_setprio(0);
    }
  }
  float rsum = rs0 + rs1;
  rsum += __shfl_xor(rsum, 32);
  float invq = 1.0f / rsum;
  #pragma unroll
  for (int r = 0; r < 16; ++r) {
    const int qr = (r & 3) + 8 * (r >> 2) + 4 * hi;
    float inv = __shfl(invq, qr);
    size_t base = (size_t)(r0w + qr) * 1024 + h * DHEAD + l32;
    cat[base] = f2bf(o0[r] * inv);
    cat[base + 32] = f2bf(o1[r] * inv);
  }
}

// ================= host ====================================================================
extern "C" void kernel_launch(void* const* d_in, const int* in_sizes, int n_in,
                              void* d_out, int out_size, void* d_ws, size_t ws_size,
                              hipStream_t stream) {
  const float* gene = (const float*)d_in[0];
  const float* drug = (const float*)d_in[1];
  const float* lng_g = (const float*)d_in[2];
  const float* lng_b = (const float*)d_in[3];
  const float* lnd_g = (const float*)d_in[4];
  const float* lnd_b = (const float*)d_in[5];
  const float* wgq = (const float*)d_in[6];  const float* bgq = (const float*)d_in[7];
  const float* wgk = (const float*)d_in[8];  const float* bgk = (const float*)d_in[9];
  const float* wgv = (const float*)d_in[10]; const float* bgv = (const float*)d_in[11];
  const float* wdq = (const float*)d_in[12]; const float* bdq = (const float*)d_in[13];
  const float* wdk = (const float*)d_in[14]; const float* bdk = (const float*)d_in[15];
  const float* wdv = (const float*)d_in[16]; const float* bdv = (const float*)d_in[17];
  const float* wo  = (const float*)d_in[18]; const float* bo  = (const float*)d_in[19];
  const float* wgg = (const float*)d_in[20]; const float* bgg = (const float*)d_in[21];
  const float* gg_g = (const float*)d_in[22]; const float* gg_b = (const float*)d_in[23];
  const float* wdg = (const float*)d_in[24]; const float* bdg = (const float*)d_in[25];
  const float* dg_g = (const float*)d_in[26]; const float* dg_b = (const float*)d_in[27];
  float* out = (float*)d_out;

  char* p = (char*)d_ws;
  size_t off = 0;
  auto alloc = [&](size_t bytes) { char* r = p + off; off = (off + bytes + 255) & ~(size_t)255; return r; };
  ushort* wT_gq = (ushort*)alloc(512 * 512 * 2);
  ushort* wT_gk = (ushort*)alloc(512 * 512 * 2);
  ushort* wT_gv = (ushort*)alloc(512 * 512 * 2);
  ushort* wT_dq = (ushort*)alloc(512 * 512 * 2);
  ushort* wT_dk = (ushort*)alloc(512 * 512 * 2);
  ushort* wT_dv = (ushort*)alloc(512 * 512 * 2);
  ushort* wT_o  = (ushort*)alloc(512 * 512 * 2);
  ushort* wT_gg = (ushort*)alloc(1024 * 512 * 2);
  ushort* wT_dg = (ushort*)alloc(1024 * 512 * 2);
  ushort* ng   = (ushort*)alloc((size_t)SGQ * 512 * 2);
  ushort* nd   = (ushort*)alloc((size_t)SGQ * 512 * 2);
  ushort* catg = (ushort*)alloc((size_t)SGQ * 1024 * 2);
  ushort* catd = (ushort*)alloc((size_t)SGQ * 1024 * 2);
  ushort* qn_g = (ushort*)alloc((size_t)SGQ * 512 * 2);
  ushort* kn_g = (ushort*)alloc((size_t)SGQ * 512 * 2);
  ushort* qn_d = (ushort*)alloc((size_t)SGQ * 512 * 2);
  ushort* kn_d = (ushort*)alloc((size_t)SGQ * 512 * 2);
  ushort* vt_g = (ushort*)alloc((size_t)SGQ * 512 * 2);
  ushort* vt_d = (ushort*)alloc((size_t)SGQ * 512 * 2);
  // dead-buffer reuse after attention:
  float*  tmpF_g = (float*)qn_g;   // 8 MB spans qn_g+kn_g (contiguous, 256-aligned)
  float*  tmpF_d = (float*)qn_d;   // 8 MB spans qn_d+kn_d
  ushort* gate_g = vt_g;
  ushort* gate_d = vt_d;

  dim3 blk(256);

  WArgs wa;
  {
    const float* ws_[9] = {wgq, wgk, wgv, wdq, wdk, wdv, wo, wgg, wdg};
    ushort* wt_[9] = {wT_gq, wT_gk, wT_gv, wT_dq, wT_dk, wT_dv, wT_o, wT_gg, wT_dg};
    int k_[9] = {512, 512, 512, 512, 512, 512, 512, 1024, 1024};
    for (int i = 0; i < 9; ++i) { wa.w[i] = ws_[i]; wa.wt[i] = wt_[i]; wa.K[i] = k_[i]; }
  }
  wconv_kernel<<<dim3(16, 32, 9), blk, 0, stream>>>(wa);

  LArgs la;
  la.x[0] = gene; la.x[1] = drug;
  la.gg[0] = lng_g; la.gg[1] = lnd_g;
  la.bb[0] = lng_b; la.bb[1] = lnd_b;
  la.normed[0] = ng; la.normed[1] = nd;
  la.cat[0] = catg; la.cat[1] = catd;
  ln_prep_kernel<<<dim3(1024, 2), blk, 0, stream>>>(la);

  GemmArgs qa;
  {
    const ushort* A_[6] = {ng, ng, catg + 512, nd, nd, catd + 512};
    const ushort* W_[6] = {wT_gq, wT_gk, wT_gv, wT_dq, wT_dk, wT_dv};
    const float* B_[6] = {bgq, bgk, bgv, bdq, bdk, bdv};
    ushort* D_[6] = {qn_g, kn_g, vt_g, qn_d, kn_d, vt_d};
    int lda_[6] = {512, 512, 1024, 512, 512, 1024};
    float sc_[6] = {0.125f, 1.0f, 0.f, 0.125f, 1.0f, 0.f};
    int iv_[6] = {0, 0, 1, 0, 0, 1};
    for (int i = 0; i < 6; ++i) {
      qa.d[i].A = A_[i]; qa.d[i].Wt = W_[i]; qa.d[i].bias = B_[i];
      qa.d[i].dst = D_[i]; qa.d[i].emb = nullptr; qa.d[i].gate = nullptr;
      qa.d[i].lda = lda_[i]; qa.d[i].K = 512; qa.d[i].scale = sc_[i]; qa.d[i].isV = iv_[i];
    }
  }
  gemm_tiled<0><<<dim3(4, 32, 6), blk, 0, stream>>>(qa);

  AArgs aa;
  aa.qn[0] = qn_g; aa.qn[1] = qn_d;
  aa.kn[0] = kn_d; aa.kn[1] = kn_g;   // cross: gene-q attends drug-K/V, and vice versa
  aa.vt[0] = vt_d; aa.vt[1] = vt_g;
  aa.cat[0] = catg; aa.cat[1] = catd;
  attn_kernel<<<dim3(32, 8, 2), blk, 0, stream>>>(aa);

  GemmArgs ga;
  {
    const ushort* A_[2] = {catg, catd};
    const ushort* W_[2] = {wT_gg, wT_dg};
    const float* B_[2] = {bgg, bdg};
    float* D_[2] = {tmpF_g, tmpF_d};
    for (int i = 0; i < 2; ++i) {
      ga.d[i].A = A_[i]; ga.d[i].Wt = W_[i]; ga.d[i].bias = B_[i];
      ga.d[i].dst = D_[i]; ga.d[i].emb = nullptr; ga.d[i].gate = nullptr;
      ga.d[i].lda = 1024; ga.d[i].K = 1024; ga.d[i].scale = 0.f; ga.d[i].isV = 0;
    }
  }
  gemm_tiled<1><<<dim3(4, 32, 2), blk, 0, stream>>>(ga);

  SArgs sa;
  sa.x[0] = tmpF_g; sa.x[1] = tmpF_d;
  sa.gg[0] = gg_g; sa.gg[1] = dg_g;
  sa.bb[0] = gg_b; sa.bb[1] = dg_b;
  sa.gate[0] = gate_g; sa.gate[1] = gate_d;
  ln_sigmoid_kernel<<<dim3(1024, 2), blk, 0, stream>>>(sa);

  GemmArgs oa;
  {
    const ushort* A_[2] = {catg, catd};
    const float* E_[2] = {gene, drug};
    const ushort* G_[2] = {gate_g, gate_d};
    float* D_[2] = {out, out + (size_t)SGQ * 512};
    for (int i = 0; i < 2; ++i) {
      oa.d[i].A = A_[i]; oa.d[i].Wt = wT_o; oa.d[i].bias = bo;
      oa.d[i].dst = D_[i]; oa.d[i].emb = E_[i]; oa.d[i].gate = G_[i];
      oa.d[i].lda = 1024; oa.d[i].K = 512; oa.d[i].scale = 0.f; oa.d[i].isV = 0;
    }
  }
  gemm_tiled<2><<<dim3(4, 32, 2), blk, 0, stream>>>(oa);
}

// Round 5
// 181.574 us; speedup vs baseline: 4.6945x; 1.0080x over previous
//
#include <hip/hip_runtime.h>
#include <hip/hip_bf16.h>

#define SGQ 4096
#define DMODEL 512
#define NH 8
#define DHEAD 64

typedef __attribute__((ext_vector_type(8))) short s16x8;
typedef __attribute__((ext_vector_type(4))) float f32x4;
typedef __attribute__((ext_vector_type(16))) float f32x16;
typedef __attribute__((ext_vector_type(4))) unsigned int u32x4;

__device__ inline ushort f2bf(float x) {
  unsigned u = __float_as_uint(x);
  return (ushort)((u + 0x7FFFu + ((u >> 16) & 1u)) >> 16);
}
__device__ inline float bf2f(ushort h) { return __uint_as_float(((unsigned)h) << 16); }
__device__ inline float exp2_hw(float x) {  // v_exp_f32 computes 2^x
  float r; asm("v_exp_f32 %0, %1" : "=v"(r) : "v"(x)); return r;
}
__device__ inline void gload16(const ushort* g, ushort* l) {
  __builtin_amdgcn_global_load_lds((const __attribute__((address_space(1))) void*)g,
                                   (__attribute__((address_space(3))) void*)l, 16, 0, 0);
}
// conflict-free row->granule swizzle: injective on {a..a+3}u{a+8..a+11} and {a..a+7}
#define SWX(row) (((row) & 7) ^ (((row) >> 1) & 4))

// ================= merged weight convert+transpose: W[K][N] f32 -> Wt[N][K] bf16 ===========
struct WArgs { const float* w[9]; ushort* wt[9]; int K[9]; };

__global__ __launch_bounds__(256) void wconv_kernel(WArgs args) {
  __shared__ float tile[32][33];
  int z = blockIdx.z;
  int K = args.K[z];
  int k0 = blockIdx.y * 32;
  if (k0 >= K) return;
  const float* W = args.w[z];
  ushort* Wt = args.wt[z];
  int n0 = blockIdx.x * 32;
  int tx = threadIdx.x & 31, ty = threadIdx.x >> 5;
  #pragma unroll
  for (int i = ty; i < 32; i += 8) tile[i][tx] = W[(size_t)(k0 + i) * DMODEL + n0 + tx];
  __syncthreads();
  #pragma unroll
  for (int i = ty; i < 32; i += 8) Wt[(size_t)(n0 + i) * K + k0 + tx] = f2bf(tile[tx][i]);
}

// ================= LayerNorm -> normed bf16; embeds bf16 -> cat[:,512:] (both sides) ======
struct LArgs { const float* x[2]; const float* gg[2]; const float* bb[2]; ushort* normed[2]; ushort* cat[2]; };

__global__ __launch_bounds__(256) void ln_prep_kernel(LArgs args) {
  int side = blockIdx.y;
  int row = blockIdx.x * 4 + (threadIdx.x >> 6);
  int lane = threadIdx.x & 63;
  const float* xr = args.x[side] + (size_t)row * DMODEL + lane * 8;
  float4 p0 = *(const float4*)xr;
  float4 p1 = *(const float4*)(xr + 4);
  float v[8] = {p0.x, p0.y, p0.z, p0.w, p1.x, p1.y, p1.z, p1.w};
  float s = 0.f;
  #pragma unroll
  for (int j = 0; j < 8; ++j) s += v[j];
  #pragma unroll
  for (int m = 1; m <= 32; m <<= 1) s += __shfl_xor(s, m);
  float mu = s * (1.0f / DMODEL);
  float q = 0.f;
  #pragma unroll
  for (int j = 0; j < 8; ++j) { float d = v[j] - mu; q += d * d; }
  #pragma unroll
  for (int m = 1; m <= 32; m <<= 1) q += __shfl_xor(q, m);
  float rs = rsqrtf(q * (1.0f / DMODEL) + 1e-5f);
  const float* g = args.gg[side];
  const float* b = args.bb[side];
  s16x8 nout, eout;
  #pragma unroll
  for (int j = 0; j < 8; ++j) {
    int c = lane * 8 + j;
    nout[j] = (short)f2bf((v[j] - mu) * rs * g[c] + b[c]);
    eout[j] = (short)f2bf(v[j]);
  }
  *(s16x8*)(args.normed[side] + (size_t)row * DMODEL + lane * 8) = nout;
  *(s16x8*)(args.cat[side] + (size_t)row * 1024 + DMODEL + lane * 8) = eout;
}

// ================= LayerNorm + sigmoid -> gate bf16 (both sides) ==========================
struct SArgs { const float* x[2]; const float* gg[2]; const float* bb[2]; ushort* gate[2]; };

__global__ __launch_bounds__(256) void ln_sigmoid_kernel(SArgs args) {
  int side = blockIdx.y;
  int row = blockIdx.x * 4 + (threadIdx.x >> 6);
  int lane = threadIdx.x & 63;
  const float* xr = args.x[side] + (size_t)row * DMODEL + lane * 8;
  float4 p0 = *(const float4*)xr;
  float4 p1 = *(const float4*)(xr + 4);
  float v[8] = {p0.x, p0.y, p0.z, p0.w, p1.x, p1.y, p1.z, p1.w};
  float s = 0.f;
  #pragma unroll
  for (int j = 0; j < 8; ++j) s += v[j];
  #pragma unroll
  for (int m = 1; m <= 32; m <<= 1) s += __shfl_xor(s, m);
  float mu = s * (1.0f / DMODEL);
  float q = 0.f;
  #pragma unroll
  for (int j = 0; j < 8; ++j) { float d = v[j] - mu; q += d * d; }
  #pragma unroll
  for (int m = 1; m <= 32; m <<= 1) q += __shfl_xor(q, m);
  float rs = rsqrtf(q * (1.0f / DMODEL) + 1e-5f);
  const float* g = args.gg[side];
  const float* b = args.bb[side];
  s16x8 o;
  #pragma unroll
  for (int j = 0; j < 8; ++j) {
    int c = lane * 8 + j;
    float y = (v[j] - mu) * rs * g[c] + b[c];
    o[j] = (short)f2bf(1.0f / (1.0f + __expf(-y)));
  }
  *(s16x8*)(args.gate[side] + (size_t)row * DMODEL + lane * 8) = o;
}

// ================= unified 128x128-tile GEMM, global_load_lds staging (m97 structure) =====
// C = A[M x K](bf16, lda) @ Wt[N][K]^T.  4 waves, each owns a 64x64 quadrant.
// EPI 0: qkv (isV? transposed-V write : per-head l2norm+scale write)
// EPI 1: f32 out (gate pre-LN).  EPI 2: out = emb + gate * (acc + bias)
struct GemmDesc {
  const ushort* A; const ushort* Wt; const float* bias;
  void* dst; const float* emb; const ushort* gate;
  int lda; int K; float scale; int isV;
};
struct GemmArgs { GemmDesc d[6]; };

template <int EPI>
__global__ __launch_bounds__(256, 2) void gemm_tiled(GemmArgs args) {
  __shared__ __align__(16) ushort Ash[2][128 * 32];
  __shared__ __align__(16) ushort Bsh[2][128 * 32];
  const GemmDesc& D = args.d[blockIdx.z];
  const int tid = threadIdx.x;
  const int w = tid >> 6, lane = tid & 63;
  const int ln = lane & 15, g = lane >> 4;
  const int wr = w >> 1, wc = w & 1;
  const int rowT = blockIdx.y * 128, colT = blockIdx.x * 128;
  const int K = D.K, lda = D.lda;
  const int srow = lane >> 2, scol = (lane & 3) * 8;

  f32x4 zero = {0.f, 0.f, 0.f, 0.f};
  f32x4 acc[4][4];
  #pragma unroll
  for (int m = 0; m < 4; ++m)
    #pragma unroll
    for (int n = 0; n < 4; ++n) acc[m][n] = zero;

  // wave w stages rows [c*64 + w*16, +16) of both tiles; lds dest linear, lane x 16B
  auto stage = [&](int cur, int k0) {
    #pragma unroll
    for (int c = 0; c < 2; ++c) {
      const int rbase = c * 64 + w * 16;
      gload16(D.A + (size_t)(rowT + rbase + srow) * lda + k0 + scol, &Ash[cur][rbase * 32]);
      gload16(D.Wt + (size_t)(colT + rbase + srow) * K + k0 + scol, &Bsh[cur][rbase * 32]);
    }
  };

  stage(0, 0);
  const int nT = K >> 5;
  for (int t = 0; t < nT; ++t) {
    const int cur = t & 1;
    __syncthreads();                       // drains vmcnt: tile t staged & prev reads done
    if (t + 1 < nT) stage(cur ^ 1, (t + 1) * 32);
    s16x8 af[4], bf[4];
    #pragma unroll
    for (int m = 0; m < 4; ++m) {
      af[m] = *(const s16x8*)&Ash[cur][(wr * 64 + m * 16 + ln) * 32 + g * 8];
      bf[m] = *(const s16x8*)&Bsh[cur][(wc * 64 + m * 16 + ln) * 32 + g * 8];
    }
    #pragma unroll
    for (int m = 0; m < 4; ++m)
      #pragma unroll
      for (int n = 0; n < 4; ++n)
        acc[m][n] = __builtin_amdgcn_mfma_f32_16x16x32_bf16(af[m], bf[n], acc[m][n], 0, 0, 0);
  }

  const float* bias = D.bias;
  const int colw = colT + wc * 64;
  if (EPI == 0) {
    const int h = colw >> 6;
    if (!D.isV) {
      float sc[4][4];
      #pragma unroll
      for (int m = 0; m < 4; ++m) {
        float ss[4] = {0.f, 0.f, 0.f, 0.f};
        #pragma unroll
        for (int n = 0; n < 4; ++n) {
          float bv = bias[colw + n * 16 + ln];
          #pragma unroll
          for (int r = 0; r < 4; ++r) {
            float v = acc[m][n][r] + bv;
            acc[m][n][r] = v;
            ss[r] += v * v;
          }
        }
        #pragma unroll
        for (int r = 0; r < 4; ++r) {
          float v = ss[r];
          v += __shfl_xor(v, 1); v += __shfl_xor(v, 2);
          v += __shfl_xor(v, 4); v += __shfl_xor(v, 8);
          sc[m][r] = D.scale / fmaxf(sqrtf(v), 1e-12f);
        }
      }
      ushort* dst = (ushort*)D.dst;
      #pragma unroll
      for (int m = 0; m < 4; ++m)
        #pragma unroll
        for (int n = 0; n < 4; ++n)
          #pragma unroll
          for (int r = 0; r < 4; ++r) {
            int row = rowT + wr * 64 + m * 16 + g * 4 + r;
            dst[((size_t)h * SGQ + row) * DHEAD + n * 16 + ln] = f2bf(acc[m][n][r] * sc[m][r]);
          }
    } else {
      ushort* dst = (ushort*)D.dst;
      #pragma unroll
      for (int m = 0; m < 4; ++m)
        #pragma unroll
        for (int n = 0; n < 4; ++n) {
          int d = n * 16 + ln;
          float bv = bias[colw + d];
          uint lo = (uint)f2bf(acc[m][n][0] + bv) | ((uint)f2bf(acc[m][n][1] + bv) << 16);
          uint hi2 = (uint)f2bf(acc[m][n][2] + bv) | ((uint)f2bf(acc[m][n][3] + bv) << 16);
          int s0 = rowT + wr * 64 + m * 16 + g * 4;
          uint2 pk; pk.x = lo; pk.y = hi2;
          *(uint2*)(dst + (size_t)(h * DHEAD + d) * SGQ + s0) = pk;
        }
    }
  } else if (EPI == 1) {
    float* outF = (float*)D.dst;
    #pragma unroll
    for (int m = 0; m < 4; ++m)
      #pragma unroll
      for (int n = 0; n < 4; ++n) {
        float bv = bias[colw + n * 16 + ln];
        #pragma unroll
        for (int r = 0; r < 4; ++r)
          outF[(size_t)(rowT + wr * 64 + m * 16 + g * 4 + r) * DMODEL + colw + n * 16 + ln] =
              acc[m][n][r] + bv;
      }
  } else {
    float* outO = (float*)D.dst;
    #pragma unroll
    for (int m = 0; m < 4; ++m)
      #pragma unroll
      for (int n = 0; n < 4; ++n) {
        float bv = bias[colw + n * 16 + ln];
        #pragma unroll
        for (int r = 0; r < 4; ++r) {
          size_t idx = (size_t)(rowT + wr * 64 + m * 16 + g * 4 + r) * DMODEL + colw + n * 16 + ln;
          outO[idx] = D.emb[idx] + bf2f(D.gate[idx]) * (acc[m][n][r] + bv);
        }
      }
  }
}

// ================= attention: 32x32 swapped-operand MFMA, P in registers =================
// qn[s]: [H][Sq][64] (l2*0.125*log2e -> scores in exp2 domain), kn: [H][Sk][64],
// vt: [H][64][Sk].  S^T = mfma(A=K_perm, B=Q); bit2<->3-swapped A rows make each lane's
// 16 C regs consecutive-k; cvt_pk pairs feed PV's A-fragment directly.
struct AArgs { const ushort* qn[2]; const ushort* kn[2]; const ushort* vt[2]; ushort* cat[2]; };

__global__ __launch_bounds__(256, 2) void attn_kernel(AArgs args) {
  __shared__ __align__(16) ushort Ksh[2][64 * 64];
  __shared__ __align__(16) ushort Vsh[2][64 * 64];
  const int side = blockIdx.z, h = blockIdx.y, qb = blockIdx.x;
  const int w = threadIdx.x >> 6, lane = threadIdx.x & 63;
  const int l32 = lane & 31, hi = lane >> 5;
  const int l8 = lane & 7, lr = lane >> 3;
  const ushort* qnh = args.qn[side] + (size_t)h * SGQ * DHEAD;
  const ushort* knh = args.kn[side] + (size_t)h * SGQ * DHEAD;
  const ushort* vth = args.vt[side] + (size_t)h * DHEAD * SGQ;
  ushort* cat = args.cat[side];
  const int r0w = qb * 128 + w * 32;

  s16x8 qf[4];
  #pragma unroll
  for (int s = 0; s < 4; ++s)
    qf[s] = *(const s16x8*)(qnh + (size_t)(r0w + l32) * DHEAD + s * 16 + hi * 8);

  const int krow0 = w * 16;  // this wave stages K/V rows [krow0, krow0+16)
  s16x8 sk[2], sv[2];
  #pragma unroll
  for (int c = 0; c < 2; ++c) {
    int row = krow0 + c * 8 + lr;
    sk[c] = *(const s16x8*)(knh + (size_t)row * DHEAD + l8 * 8);
    sv[c] = *(const s16x8*)(vth + (size_t)row * SGQ + l8 * 8);
  }

  const f32x16 Z = {0,0,0,0,0,0,0,0,0,0,0,0,0,0,0,0};
  f32x16 o0 = Z, o1 = Z;
  float rs0 = 0.f, rs1 = 0.f;
  const int krp = (l32 & 19) | ((l32 & 4) << 1) | ((l32 & 8) >> 1);  // swap bits 2<->3

  for (int t = 0; t < SGQ / 64; ++t) {
    const int cur = t & 1;
    #pragma unroll
    for (int c = 0; c < 2; ++c) {
      int row = krow0 + c * 8 + lr;
      int colsw = (l8 ^ SWX(row)) * 8;
      *(s16x8*)&Ksh[cur][row * 64 + colsw] = sk[c];
      *(s16x8*)&Vsh[cur][row * 64 + colsw] = sv[c];
    }
    asm volatile("s_waitcnt lgkmcnt(0)" ::: "memory");
    __builtin_amdgcn_s_barrier();
    asm volatile("" ::: "memory");
    if (t < SGQ / 64 - 1) {
      const int key0 = (t + 1) << 6;
      #pragma unroll
      for (int c = 0; c < 2; ++c) {
        int row = krow0 + c * 8 + lr;
        sk[c] = *(const s16x8*)(knh + (size_t)(key0 + row) * DHEAD + l8 * 8);
        sv[c] = *(const s16x8*)(vth + (size_t)row * SGQ + key0 + l8 * 8);
      }
    }
    #pragma unroll
    for (int st = 0; st < 2; ++st) {
      const int kr = st * 32 + krp;
      const int rsw = SWX(kr);
      f32x16 S = Z;
      __builtin_amdgcn_s_setprio(1);
      #pragma unroll
      for (int s = 0; s < 4; ++s) {
        s16x8 ka = *(const s16x8*)&Ksh[cur][kr * 64 + ((s * 2 + hi) ^ rsw) * 8];
        S = __builtin_amdgcn_mfma_f32_32x32x16_bf16(ka, qf[s], S, 0, 0, 0);
      }
      __builtin_amdgcn_s_setprio(0);
      // clip(-10,10) is a provable no-op; scores pre-scaled by log2e -> exp2 directly
      float p[16];
      #pragma unroll
      for (int i = 0; i < 16; ++i) p[i] = exp2_hw(S[i]);
      #pragma unroll
      for (int i = 0; i < 16; i += 2) { rs0 += p[i]; rs1 += p[i + 1]; }
      uint u[8];
      #pragma unroll
      for (int j = 0; j < 8; ++j) {
        uint r_;
        asm("v_cvt_pk_bf16_f32 %0, %1, %2" : "=v"(r_) : "v"(p[2 * j]), "v"(p[2 * j + 1]));
        u[j] = r_;
      }
      __builtin_amdgcn_s_setprio(1);
      #pragma unroll
      for (int slot = 0; slot < 2; ++slot) {
        u32x4 uv = {u[slot * 4 + 0], u[slot * 4 + 1], u[slot * 4 + 2], u[slot * 4 + 3]};
        s16x8 pf = __builtin_bit_cast(s16x8, uv);
        const int kcg = st * 4 + slot * 2 + hi;   // k col granule
        {
          int vr = l32;
          s16x8 vb = *(const s16x8*)&Vsh[cur][vr * 64 + ((kcg ^ SWX(vr)) * 8)];
          o0 = __builtin_amdgcn_mfma_f32_32x32x16_bf16(pf, vb, o0, 0, 0, 0);
        }
        {
          int vr = 32 + l32;
          s16x8 vb = *(const s16x8*)&Vsh[cur][vr * 64 + ((kcg ^ SWX(vr)) * 8)];
          o1 = __builtin_amdgcn_mfma_f32_32x32x16_bf16(pf, vb, o1, 0, 0, 0);
        }
      }
      __builtin_amdgcn_s_setprio(0);
    }
  }
  float rsum = rs0 + rs1;
  rsum += __shfl_xor(rsum, 32);
  float invq = 1.0f / rsum;
  #pragma unroll
  for (int r = 0; r < 16; ++r) {
    const int qr = (r & 3) + 8 * (r >> 2) + 4 * hi;
    float inv = __shfl(invq, qr);
    size_t base = (size_t)(r0w + qr) * 1024 + h * DHEAD + l32;
    cat[base] = f2bf(o0[r] * inv);
    cat[base + 32] = f2bf(o1[r] * inv);
  }
}

// ================= host ====================================================================
extern "C" void kernel_launch(void* const* d_in, const int* in_sizes, int n_in,
                              void* d_out, int out_size, void* d_ws, size_t ws_size,
                              hipStream_t stream) {
  const float* gene = (const float*)d_in[0];
  const float* drug = (const float*)d_in[1];
  const float* lng_g = (const float*)d_in[2];
  const float* lng_b = (const float*)d_in[3];
  const float* lnd_g = (const float*)d_in[4];
  const float* lnd_b = (const float*)d_in[5];
  const float* wgq = (const float*)d_in[6];  const float* bgq = (const float*)d_in[7];
  const float* wgk = (const float*)d_in[8];  const float* bgk = (const float*)d_in[9];
  const float* wgv = (const float*)d_in[10]; const float* bgv = (const float*)d_in[11];
  const float* wdq = (const float*)d_in[12]; const float* bdq = (const float*)d_in[13];
  const float* wdk = (const float*)d_in[14]; const float* bdk = (const float*)d_in[15];
  const float* wdv = (const float*)d_in[16]; const float* bdv = (const float*)d_in[17];
  const float* wo  = (const float*)d_in[18]; const float* bo  = (const float*)d_in[19];
  const float* wgg = (const float*)d_in[20]; const float* bgg = (const float*)d_in[21];
  const float* gg_g = (const float*)d_in[22]; const float* gg_b = (const float*)d_in[23];
  const float* wdg = (const float*)d_in[24]; const float* bdg = (const float*)d_in[25];
  const float* dg_g = (const float*)d_in[26]; const float* dg_b = (const float*)d_in[27];
  float* out = (float*)d_out;

  char* p = (char*)d_ws;
  size_t off = 0;
  auto alloc = [&](size_t bytes) { char* r = p + off; off = (off + bytes + 255) & ~(size_t)255; return r; };
  ushort* wT_gq = (ushort*)alloc(512 * 512 * 2);
  ushort* wT_gk = (ushort*)alloc(512 * 512 * 2);
  ushort* wT_gv = (ushort*)alloc(512 * 512 * 2);
  ushort* wT_dq = (ushort*)alloc(512 * 512 * 2);
  ushort* wT_dk = (ushort*)alloc(512 * 512 * 2);
  ushort* wT_dv = (ushort*)alloc(512 * 512 * 2);
  ushort* wT_o  = (ushort*)alloc(512 * 512 * 2);
  ushort* wT_gg = (ushort*)alloc(1024 * 512 * 2);
  ushort* wT_dg = (ushort*)alloc(1024 * 512 * 2);
  ushort* ng   = (ushort*)alloc((size_t)SGQ * 512 * 2);
  ushort* nd   = (ushort*)alloc((size_t)SGQ * 512 * 2);
  ushort* catg = (ushort*)alloc((size_t)SGQ * 1024 * 2);
  ushort* catd = (ushort*)alloc((size_t)SGQ * 1024 * 2);
  ushort* qn_g = (ushort*)alloc((size_t)SGQ * 512 * 2);
  ushort* kn_g = (ushort*)alloc((size_t)SGQ * 512 * 2);
  ushort* qn_d = (ushort*)alloc((size_t)SGQ * 512 * 2);
  ushort* kn_d = (ushort*)alloc((size_t)SGQ * 512 * 2);
  ushort* vt_g = (ushort*)alloc((size_t)SGQ * 512 * 2);
  ushort* vt_d = (ushort*)alloc((size_t)SGQ * 512 * 2);
  // dead-buffer reuse after attention:
  float*  tmpF_g = (float*)qn_g;   // 8 MB spans qn_g+kn_g (contiguous, 256-aligned)
  float*  tmpF_d = (float*)qn_d;   // 8 MB spans qn_d+kn_d
  ushort* gate_g = vt_g;
  ushort* gate_d = vt_d;

  dim3 blk(256);
  const float QSCALE = 0.125f * 1.4426950408889634f;  // head-scale * log2(e)

  WArgs wa;
  {
    const float* ws_[9] = {wgq, wgk, wgv, wdq, wdk, wdv, wo, wgg, wdg};
    ushort* wt_[9] = {wT_gq, wT_gk, wT_gv, wT_dq, wT_dk, wT_dv, wT_o, wT_gg, wT_dg};
    int k_[9] = {512, 512, 512, 512, 512, 512, 512, 1024, 1024};
    for (int i = 0; i < 9; ++i) { wa.w[i] = ws_[i]; wa.wt[i] = wt_[i]; wa.K[i] = k_[i]; }
  }
  wconv_kernel<<<dim3(16, 32, 9), blk, 0, stream>>>(wa);

  LArgs la;
  la.x[0] = gene; la.x[1] = drug;
  la.gg[0] = lng_g; la.gg[1] = lnd_g;
  la.bb[0] = lng_b; la.bb[1] = lnd_b;
  la.normed[0] = ng; la.normed[1] = nd;
  la.cat[0] = catg; la.cat[1] = catd;
  ln_prep_kernel<<<dim3(1024, 2), blk, 0, stream>>>(la);

  GemmArgs qa;
  {
    const ushort* A_[6] = {ng, ng, catg + 512, nd, nd, catd + 512};
    const ushort* W_[6] = {wT_gq, wT_gk, wT_gv, wT_dq, wT_dk, wT_dv};
    const float* B_[6] = {bgq, bgk, bgv, bdq, bdk, bdv};
    ushort* D_[6] = {qn_g, kn_g, vt_g, qn_d, kn_d, vt_d};
    int lda_[6] = {512, 512, 1024, 512, 512, 1024};
    float sc_[6] = {QSCALE, 1.0f, 0.f, QSCALE, 1.0f, 0.f};
    int iv_[6] = {0, 0, 1, 0, 0, 1};
    for (int i = 0; i < 6; ++i) {
      qa.d[i].A = A_[i]; qa.d[i].Wt = W_[i]; qa.d[i].bias = B_[i];
      qa.d[i].dst = D_[i]; qa.d[i].emb = nullptr; qa.d[i].gate = nullptr;
      qa.d[i].lda = lda_[i]; qa.d[i].K = 512; qa.d[i].scale = sc_[i]; qa.d[i].isV = iv_[i];
    }
  }
  gemm_tiled<0><<<dim3(4, 32, 6), blk, 0, stream>>>(qa);

  AArgs aa;
  aa.qn[0] = qn_g; aa.qn[1] = qn_d;
  aa.kn[0] = kn_d; aa.kn[1] = kn_g;   // cross: gene-q attends drug-K/V, and vice versa
  aa.vt[0] = vt_d; aa.vt[1] = vt_g;
  aa.cat[0] = catg; aa.cat[1] = catd;
  attn_kernel<<<dim3(32, 8, 2), blk, 0, stream>>>(aa);

  GemmArgs ga;
  {
    const ushort* A_[2] = {catg, catd};
    const ushort* W_[2] = {wT_gg, wT_dg};
    const float* B_[2] = {bgg, bdg};
    float* D_[2] = {tmpF_g, tmpF_d};
    for (int i = 0; i < 2; ++i) {
      ga.d[i].A = A_[i]; ga.d[i].Wt = W_[i]; ga.d[i].bias = B_[i];
      ga.d[i].dst = D_[i]; ga.d[i].emb = nullptr; ga.d[i].gate = nullptr;
      ga.d[i].lda = 1024; ga.d[i].K = 1024; ga.d[i].scale = 0.f; ga.d[i].isV = 0;
    }
  }
  gemm_tiled<1><<<dim3(4, 32, 2), blk, 0, stream>>>(ga);

  SArgs sa;
  sa.x[0] = tmpF_g; sa.x[1] = tmpF_d;
  sa.gg[0] = gg_g; sa.gg[1] = dg_g;
  sa.bb[0] = gg_b; sa.bb[1] = dg_b;
  sa.gate[0] = gate_g; sa.gate[1] = gate_d;
  ln_sigmoid_kernel<<<dim3(1024, 2), blk, 0, stream>>>(sa);

  GemmArgs oa;
  {
    const ushort* A_[2] = {catg, catd};
    const float* E_[2] = {gene, drug};
    const ushort* G_[2] = {gate_g, gate_d};
    float* D_[2] = {out, out + (size_t)SGQ * 512};
    for (int i = 0; i < 2; ++i) {
      oa.d[i].A = A_[i]; oa.d[i].Wt = wT_o; oa.d[i].bias = bo;
      oa.d[i].dst = D_[i]; oa.d[i].emb = E_[i]; oa.d[i].gate = G_[i];
      oa.d[i].lda = 1024; oa.d[i].K = 512; oa.d[i].scale = 0.f; oa.d[i].isV = 0;
    }
  }
  gemm_tiled<2><<<dim3(4, 32, 2), blk, 0, stream>>>(oa);
}